// Round 1
// baseline (1044.593 us; speedup 1.0000x reference)
//
#include <hip/hip_runtime.h>
#include <math.h>

// ---------------- constants ----------------
// N=50000, E=800000, nfeat=256, nhid*nheads=256, nclass=40, nstruc=128, heads=8
constexpr int KDIM = 256;

// ---------------- pack W_att [8][256][32] -> Bp [256][256] (col = h*32+j) ----------------
__global__ void pack_watt(const float* __restrict__ W_att, float* __restrict__ Bp) {
  int tid = blockIdx.x * blockDim.x + threadIdx.x;
  if (tid >= 8 * 256 * 32) return;
  int j = tid & 31;
  int k = (tid >> 5) & 255;
  int h = tid >> 13;
  Bp[k * 256 + h * 32 + j] = W_att[tid];
}

// ---------------- generic K=256 GEMM: C[N,F] = A[N,256] @ B[256,F] (+bias) ----------------
template <int F, int BD, int ROWS>
__global__ __launch_bounds__(BD) void gemm_k256(const float* __restrict__ A,
                                                const float* __restrict__ B,
                                                const float* __restrict__ bias,
                                                float* __restrict__ C, int N) {
  __shared__ float sA[ROWS][KDIM];
  int n0 = blockIdx.x * ROWS;
  int t = threadIdx.x;
  for (int idx = t; idx < ROWS * KDIM; idx += BD) {
    int r = idx >> 8, k = idx & 255;
    int n = n0 + r;
    sA[r][k] = (n < N) ? A[(size_t)n * KDIM + k] : 0.f;
  }
  __syncthreads();
  if (t < F) {
    float acc[ROWS];
#pragma unroll
    for (int r = 0; r < ROWS; ++r) acc[r] = 0.f;
    for (int k4 = 0; k4 < KDIM / 4; ++k4) {
      float b0 = B[(k4 * 4 + 0) * F + t];
      float b1 = B[(k4 * 4 + 1) * F + t];
      float b2 = B[(k4 * 4 + 2) * F + t];
      float b3 = B[(k4 * 4 + 3) * F + t];
#pragma unroll
      for (int r = 0; r < ROWS; ++r) {
        const float4 a = *reinterpret_cast<const float4*>(&sA[r][k4 * 4]);
        acc[r] = fmaf(a.x, b0, fmaf(a.y, b1, fmaf(a.z, b2, fmaf(a.w, b3, acc[r]))));
      }
    }
    float bi = bias ? bias[t] : 0.f;
#pragma unroll
    for (int r = 0; r < ROWS; ++r) {
      int n = n0 + r;
      if (n < N) C[(size_t)n * F + t] = acc[r] + bi;
    }
  }
}

// ---------------- s1/s2 per node per head ----------------
__global__ void calc_s12(const float* __restrict__ H, const float* __restrict__ a1,
                         const float* __restrict__ a2, float* __restrict__ s1,
                         float* __restrict__ s2, int N) {
  int tid = blockIdx.x * blockDim.x + threadIdx.x;
  if (tid >= N * 8) return;
  int h = tid & 7;
  int n = tid >> 3;
  const float* hp = H + (size_t)n * 256 + h * 32;
  const float* A1 = a1 + h * 32;
  const float* A2 = a2 + h * 32;
  float d1 = 0.f, d2 = 0.f;
#pragma unroll
  for (int j = 0; j < 32; ++j) {
    float v = hp[j];
    d1 = fmaf(v, A1[j], d1);
    d2 = fmaf(v, A2[j], d2);
  }
  s1[tid] = d1;
  s2[tid] = d2;
}

__global__ void calc_s12_out(const float* __restrict__ Ho, const float* __restrict__ a1o,
                             const float* __restrict__ a2o, float* __restrict__ s1o,
                             float* __restrict__ s2o, int N) {
  int n = blockIdx.x * blockDim.x + threadIdx.x;
  if (n >= N) return;
  const float* hp = Ho + (size_t)n * 40;
  float d1 = 0.f, d2 = 0.f;
#pragma unroll
  for (int j = 0; j < 40; ++j) {
    float v = hp[j];
    d1 = fmaf(v, a1o[j], d1);
    d2 = fmaf(v, a2o[j], d2);
  }
  s1o[n] = d1;
  s2o[n] = d2;
}

// ---------------- CSR build ----------------
__global__ void hist_deg(const int* __restrict__ row, int* __restrict__ deg, int E) {
  int e = blockIdx.x * blockDim.x + threadIdx.x;
  if (e < E) atomicAdd(&deg[row[e]], 1);
}

__global__ void scan1(const int* __restrict__ deg, int* __restrict__ rp, int* __restrict__ bsum,
                      int N) {
  __shared__ int sd[256];
  int t = threadIdx.x;
  int i = blockIdx.x * 256 + t;
  int v = (i < N) ? deg[i] : 0;
  sd[t] = v;
  __syncthreads();
  for (int off = 1; off < 256; off <<= 1) {
    int x = (t >= off) ? sd[t - off] : 0;
    __syncthreads();
    sd[t] += x;
    __syncthreads();
  }
  if (i < N) rp[i] = sd[t] - v;  // exclusive within block
  if (t == 255) bsum[blockIdx.x] = sd[255];
}

__global__ void scan2(int* __restrict__ bsum, int nb) {
  __shared__ int sd[256];
  int t = threadIdx.x;
  int v = (t < nb) ? bsum[t] : 0;
  sd[t] = v;
  __syncthreads();
  for (int off = 1; off < 256; off <<= 1) {
    int x = (t >= off) ? sd[t - off] : 0;
    __syncthreads();
    sd[t] += x;
    __syncthreads();
  }
  if (t < nb) bsum[t] = sd[t] - v;  // exclusive block offsets
}

__global__ void scan3(int* __restrict__ rp, const int* __restrict__ bsum, int N, int E) {
  int i = blockIdx.x * 256 + threadIdx.x;
  if (i < N) rp[i] += bsum[blockIdx.x];
  if (i == 0) rp[N] = E;
}

__global__ void scatter_edges(const int* __restrict__ row, const int* __restrict__ col,
                              const int* __restrict__ rp, int* __restrict__ cur,
                              int* __restrict__ scol, int E) {
  int e = blockIdx.x * blockDim.x + threadIdx.x;
  if (e >= E) return;
  int r = row[e];
  int p = atomicAdd(&cur[r], 1);
  scol[rp[r] + p] = col[e];
}

// ---------------- GAT layer-1 aggregation (8 heads fused, F=256) ----------------
__global__ __launch_bounds__(256) void agg_att(const float* __restrict__ H,
                                               const float* __restrict__ s1,
                                               const float* __restrict__ s2,
                                               const int* __restrict__ rp,
                                               const int* __restrict__ scol,
                                               float* __restrict__ h1, int N) {
  int n = blockIdx.x;
  int t = threadIdx.x;
  int head = t >> 5;
  float s1n = s1[n * 8 + head];
  float acc = 0.f, rs = 0.f;
  int beg = rp[n], end = rp[n + 1];
  for (int i = beg; i < end; ++i) {
    int c = scol[i];
    float lg = s1n + s2[c * 8 + head];
    float lr = lg > 0.f ? lg : 0.2f * lg;
    float e = expf(-lr);
    rs += e;
    acc = fmaf(e, H[(size_t)c * 256 + t], acc);
  }
  float hp = acc / (rs + 1e-16f);
  h1[(size_t)n * 256 + t] = hp > 0.f ? hp : expm1f(hp);  // elu (concat=True)
}

// ---------------- GraphConv aggregation ----------------
__global__ __launch_bounds__(256) void agg_gc(const float* __restrict__ S,
                                              const int* __restrict__ rp,
                                              const int* __restrict__ scol,
                                              const float* __restrict__ b_gc,
                                              float* __restrict__ h2, int N) {
  int n = blockIdx.x;
  int t = threadIdx.x;
  float acc = 0.f;
  int beg = rp[n], end = rp[n + 1];
  for (int i = beg; i < end; ++i) {
    int c = scol[i];
    acc += S[(size_t)c * 256 + t];
  }
  h2[(size_t)n * 256 + t] = acc + b_gc[t];
}

// ---------------- output GAT head aggregation + elu + log_softmax (one wave/node) ----------------
__global__ __launch_bounds__(64) void agg_out_lsm(const float* __restrict__ Ho,
                                                  const float* __restrict__ s1o,
                                                  const float* __restrict__ s2o,
                                                  const int* __restrict__ rp,
                                                  const int* __restrict__ scol,
                                                  float* __restrict__ out0, int N) {
  int n = blockIdx.x;
  int t = threadIdx.x;
  float s1n = s1o[n];
  float acc = 0.f, rs = 0.f;
  int beg = rp[n], end = rp[n + 1];
  for (int i = beg; i < end; ++i) {
    int c = scol[i];
    float lg = s1n + s2o[c];
    float lr = lg > 0.f ? lg : 0.2f * lg;
    float e = expf(-lr);
    rs += e;
    if (t < 40) acc = fmaf(e, Ho[(size_t)c * 40 + t], acc);
  }
  float hp = acc / (rs + 1e-16f);
  float xo = (t < 40) ? (hp > 0.f ? hp : expm1f(hp)) : -3.0e38f;
  float mx = xo;
#pragma unroll
  for (int m = 1; m < 64; m <<= 1) mx = fmaxf(mx, __shfl_xor(mx, m));
  float ex = (t < 40) ? expf(xo - mx) : 0.f;
  float sum = ex;
#pragma unroll
  for (int m = 1; m < 64; m <<= 1) sum += __shfl_xor(sum, m);
  if (t < 40) out0[(size_t)n * 40 + t] = xo - mx - logf(sum);
}

// ---------------- launch ----------------
extern "C" void kernel_launch(void* const* d_in, const int* in_sizes, int n_in,
                              void* d_out, int out_size, void* d_ws, size_t ws_size,
                              hipStream_t stream) {
  const float* x      = (const float*)d_in[0];
  const int*   ei     = (const int*)d_in[1];
  const float* W_att  = (const float*)d_in[2];
  const float* a1     = (const float*)d_in[3];
  const float* a2     = (const float*)d_in[4];
  const float* W_out  = (const float*)d_in[5];
  const float* a1_out = (const float*)d_in[6];
  const float* a2_out = (const float*)d_in[7];
  const float* W_gc   = (const float*)d_in[8];
  const float* b_gc   = (const float*)d_in[9];
  const float* W_enc  = (const float*)d_in[10];
  const float* b_enc  = (const float*)d_in[11];

  const int N = in_sizes[0] / 256;
  const int E = in_sizes[1] / 2;
  const int* row = ei;
  const int* col = ei + E;

  char* p = (char*)d_ws;
  auto alloc = [&](size_t bytes) -> void* {
    void* r = (void*)p;
    p += (bytes + 255) & ~(size_t)255;
    return r;
  };
  float* bufA = (float*)alloc((size_t)N * 256 * 4);  // H, later support
  float* h1   = (float*)alloc((size_t)N * 256 * 4);
  float* h2   = (float*)alloc((size_t)N * 256 * 4);
  float* Ho   = (float*)alloc((size_t)N * 40 * 4);
  float* Bp   = (float*)alloc((size_t)65536 * 4);
  float* s1   = (float*)alloc((size_t)N * 8 * 4);
  float* s2   = (float*)alloc((size_t)N * 8 * 4);
  float* s1o  = (float*)alloc((size_t)N * 4);
  float* s2o  = (float*)alloc((size_t)N * 4);
  int* deg    = (int*)alloc((size_t)N * 4);
  int* rp     = (int*)alloc((size_t)(N + 1) * 4);
  int* bsum   = (int*)alloc(256 * 4);
  int* scol   = (int*)alloc((size_t)E * 4);

  float* out0 = (float*)d_out;
  float* outY = out0 + (size_t)N * 40;
  float* outZ = outY + (size_t)N * 128;

  const int nb = (N + 255) / 256;

  // CSR build (counting sort by row)
  hipMemsetAsync(deg, 0, (size_t)N * 4, stream);
  pack_watt<<<dim3((65536 + 255) / 256), dim3(256), 0, stream>>>(W_att, Bp);
  hist_deg<<<dim3((E + 255) / 256), dim3(256), 0, stream>>>(row, deg, E);
  scan1<<<dim3(nb), dim3(256), 0, stream>>>(deg, rp, bsum, N);
  scan2<<<dim3(1), dim3(256), 0, stream>>>(bsum, nb);
  scan3<<<dim3(nb), dim3(256), 0, stream>>>(rp, bsum, N, E);
  hipMemsetAsync(deg, 0, (size_t)N * 4, stream);  // reuse as cursor
  scatter_edges<<<dim3((E + 255) / 256), dim3(256), 0, stream>>>(row, col, rp, deg, scol, E);

  // layer 1: H = x @ W_att(all heads)
  gemm_k256<256, 256, 8><<<dim3((N + 7) / 8), dim3(256), 0, stream>>>(x, Bp, nullptr, bufA, N);
  calc_s12<<<dim3((N * 8 + 255) / 256), dim3(256), 0, stream>>>(bufA, a1, a2, s1, s2, N);
  agg_att<<<dim3(N), dim3(256), 0, stream>>>(bufA, s1, s2, rp, scol, h1, N);

  // GraphConv
  gemm_k256<256, 256, 8><<<dim3((N + 7) / 8), dim3(256), 0, stream>>>(h1, W_gc, nullptr, bufA, N);
  agg_gc<<<dim3(N), dim3(256), 0, stream>>>(bufA, rp, scol, b_gc, h2, N);

  // output head
  gemm_k256<40, 64, 8><<<dim3((N + 7) / 8), dim3(64), 0, stream>>>(h2, W_out, nullptr, Ho, N);
  calc_s12_out<<<dim3((N + 255) / 256), dim3(256), 0, stream>>>(Ho, a1_out, a2_out, s1o, s2o, N);
  agg_out_lsm<<<dim3(N), dim3(64), 0, stream>>>(Ho, s1o, s2o, rp, scol, out0, N);

  // y, z
  gemm_k256<128, 128, 8><<<dim3((N + 7) / 8), dim3(128), 0, stream>>>(h1, W_enc, b_enc, outY, N);
  gemm_k256<128, 128, 8><<<dim3((N + 7) / 8), dim3(128), 0, stream>>>(h2, W_enc, b_enc, outZ, N);
}

// Round 2
// 940.630 us; speedup vs baseline: 1.1105x; 1.1105x over previous
//
#include <hip/hip_runtime.h>
#include <math.h>

// N=50000, E=800000, nfeat=256, nhid*nheads=256, nclass=40, nstruc=128, heads=8
constexpr int KDIM = 256;

// ---------------- pack W_att [8][256][32] -> Bp [256][256] (col = h*32+j) ----------------
__global__ void pack_watt(const float* __restrict__ W_att, float* __restrict__ Bp) {
  int tid = blockIdx.x * blockDim.x + threadIdx.x;
  if (tid >= 8 * 256 * 32) return;
  int j = tid & 31;
  int k = (tid >> 5) & 255;
  int h = tid >> 13;
  Bp[k * 256 + h * 32 + j] = W_att[tid];
}

// ---------------- generic K=256 GEMM: C[N,F] = A[N,256] @ B[256,F] (+bias) ----------------
template <int F, int BD, int ROWS>
__global__ __launch_bounds__(BD) void gemm_k256(const float* __restrict__ A,
                                                const float* __restrict__ B,
                                                const float* __restrict__ bias,
                                                float* __restrict__ C, int N) {
  __shared__ float sA[ROWS][KDIM];
  int n0 = blockIdx.x * ROWS;
  int t = threadIdx.x;
  for (int idx = t; idx < ROWS * KDIM; idx += BD) {
    int r = idx >> 8, k = idx & 255;
    int n = n0 + r;
    sA[r][k] = (n < N) ? A[(size_t)n * KDIM + k] : 0.f;
  }
  __syncthreads();
  if (t < F) {
    float acc[ROWS];
#pragma unroll
    for (int r = 0; r < ROWS; ++r) acc[r] = 0.f;
    for (int k4 = 0; k4 < KDIM / 4; ++k4) {
      float b0 = B[(k4 * 4 + 0) * F + t];
      float b1 = B[(k4 * 4 + 1) * F + t];
      float b2 = B[(k4 * 4 + 2) * F + t];
      float b3 = B[(k4 * 4 + 3) * F + t];
#pragma unroll
      for (int r = 0; r < ROWS; ++r) {
        const float4 a = *reinterpret_cast<const float4*>(&sA[r][k4 * 4]);
        acc[r] = fmaf(a.x, b0, fmaf(a.y, b1, fmaf(a.z, b2, fmaf(a.w, b3, acc[r]))));
      }
    }
    float bi = bias ? bias[t] : 0.f;
#pragma unroll
    for (int r = 0; r < ROWS; ++r) {
      int n = n0 + r;
      if (n < N) C[(size_t)n * F + t] = acc[r] + bi;
    }
  }
}

// ---------------- s1/s2 per node per head ----------------
__global__ void calc_s12(const float* __restrict__ H, const float* __restrict__ a1,
                         const float* __restrict__ a2, float* __restrict__ s1,
                         float* __restrict__ s2, int N) {
  int tid = blockIdx.x * blockDim.x + threadIdx.x;
  if (tid >= N * 8) return;
  int h = tid & 7;
  int n = tid >> 3;
  const float* hp = H + (size_t)n * 256 + h * 32;
  const float* A1 = a1 + h * 32;
  const float* A2 = a2 + h * 32;
  float d1 = 0.f, d2 = 0.f;
#pragma unroll
  for (int j = 0; j < 32; ++j) {
    float v = hp[j];
    d1 = fmaf(v, A1[j], d1);
    d2 = fmaf(v, A2[j], d2);
  }
  s1[tid] = d1;
  s2[tid] = d2;
}

__global__ void calc_s12_out(const float* __restrict__ Ho, const float* __restrict__ a1o,
                             const float* __restrict__ a2o, float* __restrict__ s1o,
                             float* __restrict__ s2o, int N) {
  int n = blockIdx.x * blockDim.x + threadIdx.x;
  if (n >= N) return;
  const float* hp = Ho + (size_t)n * 40;
  float d1 = 0.f, d2 = 0.f;
#pragma unroll
  for (int j = 0; j < 40; ++j) {
    float v = hp[j];
    d1 = fmaf(v, a1o[j], d1);
    d2 = fmaf(v, a2o[j], d2);
  }
  s1o[n] = d1;
  s2o[n] = d2;
}

// ---------------- CSR build ----------------
__global__ void hist_deg(const int* __restrict__ row, int* __restrict__ deg, int E) {
  int e = blockIdx.x * blockDim.x + threadIdx.x;
  if (e < E) atomicAdd(&deg[row[e]], 1);
}

__global__ void scan1(const int* __restrict__ deg, int* __restrict__ rp, int* __restrict__ bsum,
                      int N) {
  __shared__ int sd[256];
  int t = threadIdx.x;
  int i = blockIdx.x * 256 + t;
  int v = (i < N) ? deg[i] : 0;
  sd[t] = v;
  __syncthreads();
  for (int off = 1; off < 256; off <<= 1) {
    int x = (t >= off) ? sd[t - off] : 0;
    __syncthreads();
    sd[t] += x;
    __syncthreads();
  }
  if (i < N) rp[i] = sd[t] - v;
  if (t == 255) bsum[blockIdx.x] = sd[255];
}

__global__ void scan2(int* __restrict__ bsum, int nb) {
  __shared__ int sd[256];
  int t = threadIdx.x;
  int v = (t < nb) ? bsum[t] : 0;
  sd[t] = v;
  __syncthreads();
  for (int off = 1; off < 256; off <<= 1) {
    int x = (t >= off) ? sd[t - off] : 0;
    __syncthreads();
    sd[t] += x;
    __syncthreads();
  }
  if (t < nb) bsum[t] = sd[t] - v;
}

__global__ void scan3(int* __restrict__ rp, const int* __restrict__ bsum, int N, int E) {
  int i = blockIdx.x * 256 + threadIdx.x;
  if (i < N) rp[i] += bsum[blockIdx.x];
  if (i == 0) rp[N] = E;
}

__global__ void scatter_edges(const int* __restrict__ row, const int* __restrict__ col,
                              const int* __restrict__ rp, int* __restrict__ cur,
                              int* __restrict__ scol, int* __restrict__ srow, int E) {
  int e = blockIdx.x * blockDim.x + threadIdx.x;
  if (e >= E) return;
  int r = row[e];
  int p = atomicAdd(&cur[r], 1);
  int idx = rp[r] + p;
  scol[idx] = col[e];
  srow[idx] = r;
}

// ---------------- edge weights: w[e][h] = exp(-lrelu(s1[r][h]+s2[c][h])) ----------------
__global__ void edge_w(const int* __restrict__ srow, const int* __restrict__ scol,
                       const float* __restrict__ s1, const float* __restrict__ s2,
                       float* __restrict__ w, int E) {
  int tid = blockIdx.x * blockDim.x + threadIdx.x;
  if (tid >= E * 8) return;
  int e = tid >> 3, h = tid & 7;
  int r = srow[e], c = scol[e];
  float lg = s1[r * 8 + h] + s2[c * 8 + h];
  float lr = lg > 0.f ? lg : 0.2f * lg;
  w[tid] = expf(-lr);
}

__global__ void edge_wo(const int* __restrict__ srow, const int* __restrict__ scol,
                        const float* __restrict__ s1o, const float* __restrict__ s2o,
                        float* __restrict__ wo, int E) {
  int e = blockIdx.x * blockDim.x + threadIdx.x;
  if (e >= E) return;
  float lg = s1o[srow[e]] + s2o[scol[e]];
  float lr = lg > 0.f ? lg : 0.2f * lg;
  wo[e] = expf(-lr);
}

// ---------------- GAT layer-1 aggregation: one wave/node, float4/lane ----------------
__global__ __launch_bounds__(64) void agg_att(const float* __restrict__ H,
                                              const float* __restrict__ w,
                                              const int* __restrict__ rp,
                                              const int* __restrict__ scol,
                                              float* __restrict__ h1, int N) {
  int n = blockIdx.x;
  int t = threadIdx.x;          // t*4 .. t*4+3 features; head = t>>3
  int head = t >> 3;
  float4 acc = {0.f, 0.f, 0.f, 0.f};
  float rs = 0.f;
  int beg = rp[n], end = rp[n + 1];
  for (int i = beg; i < end; ++i) {
    int c = scol[i];
    float wv = w[i * 8 + head];
    rs += wv;
    const float4 hv = *reinterpret_cast<const float4*>(H + (size_t)c * 256 + t * 4);
    acc.x = fmaf(wv, hv.x, acc.x);
    acc.y = fmaf(wv, hv.y, acc.y);
    acc.z = fmaf(wv, hv.z, acc.z);
    acc.w = fmaf(wv, hv.w, acc.w);
  }
  float inv = 1.f / (rs + 1e-16f);
  float4 o;
  o.x = acc.x * inv; o.y = acc.y * inv; o.z = acc.z * inv; o.w = acc.w * inv;
  o.x = o.x > 0.f ? o.x : expm1f(o.x);
  o.y = o.y > 0.f ? o.y : expm1f(o.y);
  o.z = o.z > 0.f ? o.z : expm1f(o.z);
  o.w = o.w > 0.f ? o.w : expm1f(o.w);
  *reinterpret_cast<float4*>(h1 + (size_t)n * 256 + t * 4) = o;
}

// ---------------- GraphConv aggregation: one wave/node, float4/lane ----------------
__global__ __launch_bounds__(64) void agg_gc(const float* __restrict__ S,
                                             const int* __restrict__ rp,
                                             const int* __restrict__ scol,
                                             const float* __restrict__ b_gc,
                                             float* __restrict__ h2, int N) {
  int n = blockIdx.x;
  int t = threadIdx.x;
  float4 acc = {0.f, 0.f, 0.f, 0.f};
  int beg = rp[n], end = rp[n + 1];
  for (int i = beg; i < end; ++i) {
    int c = scol[i];
    const float4 sv = *reinterpret_cast<const float4*>(S + (size_t)c * 256 + t * 4);
    acc.x += sv.x; acc.y += sv.y; acc.z += sv.z; acc.w += sv.w;
  }
  const float4 bv = *reinterpret_cast<const float4*>(b_gc + t * 4);
  float4 o = {acc.x + bv.x, acc.y + bv.y, acc.z + bv.z, acc.w + bv.w};
  *reinterpret_cast<float4*>(h2 + (size_t)n * 256 + t * 4) = o;
}

// ---------------- output head aggregation + elu + log_softmax (one wave/node) ----------------
__global__ __launch_bounds__(64) void agg_out_lsm(const float* __restrict__ Ho,
                                                  const float* __restrict__ wo,
                                                  const int* __restrict__ rp,
                                                  const int* __restrict__ scol,
                                                  float* __restrict__ out0, int N) {
  int n = blockIdx.x;
  int t = threadIdx.x;
  float acc = 0.f, rs = 0.f;
  int beg = rp[n], end = rp[n + 1];
  for (int i = beg; i < end; ++i) {
    int c = scol[i];
    float wv = wo[i];
    rs += wv;
    if (t < 40) acc = fmaf(wv, Ho[(size_t)c * 40 + t], acc);
  }
  float hp = acc / (rs + 1e-16f);
  float xo = (t < 40) ? (hp > 0.f ? hp : expm1f(hp)) : -3.0e38f;
  float mx = xo;
#pragma unroll
  for (int m = 1; m < 64; m <<= 1) mx = fmaxf(mx, __shfl_xor(mx, m));
  float ex = (t < 40) ? expf(xo - mx) : 0.f;
  float sum = ex;
#pragma unroll
  for (int m = 1; m < 64; m <<= 1) sum += __shfl_xor(sum, m);
  if (t < 40) out0[(size_t)n * 40 + t] = xo - mx - logf(sum);
}

// ---------------- launch ----------------
extern "C" void kernel_launch(void* const* d_in, const int* in_sizes, int n_in,
                              void* d_out, int out_size, void* d_ws, size_t ws_size,
                              hipStream_t stream) {
  const float* x      = (const float*)d_in[0];
  const int*   ei     = (const int*)d_in[1];
  const float* W_att  = (const float*)d_in[2];
  const float* a1     = (const float*)d_in[3];
  const float* a2     = (const float*)d_in[4];
  const float* W_out  = (const float*)d_in[5];
  const float* a1_out = (const float*)d_in[6];
  const float* a2_out = (const float*)d_in[7];
  const float* W_gc   = (const float*)d_in[8];
  const float* b_gc   = (const float*)d_in[9];
  const float* W_enc  = (const float*)d_in[10];
  const float* b_enc  = (const float*)d_in[11];

  const int N = in_sizes[0] / 256;
  const int E = in_sizes[1] / 2;
  const int* row = ei;
  const int* col = ei + E;

  char* p = (char*)d_ws;
  auto alloc = [&](size_t bytes) -> void* {
    void* r = (void*)p;
    p += (bytes + 255) & ~(size_t)255;
    return r;
  };
  float* bufA = (float*)alloc((size_t)N * 256 * 4);  // H, later support
  float* h1   = (float*)alloc((size_t)N * 256 * 4);
  float* h2   = (float*)alloc((size_t)N * 256 * 4);
  float* Ho   = (float*)alloc((size_t)N * 40 * 4);
  float* Bp   = (float*)alloc((size_t)65536 * 4);
  float* s1   = (float*)alloc((size_t)N * 8 * 4);
  float* s2   = (float*)alloc((size_t)N * 8 * 4);
  float* s1o  = (float*)alloc((size_t)N * 4);
  float* s2o  = (float*)alloc((size_t)N * 4);
  int* deg    = (int*)alloc((size_t)N * 4);
  int* rp     = (int*)alloc((size_t)(N + 1) * 4);
  int* bsum   = (int*)alloc(256 * 4);
  int* scol   = (int*)alloc((size_t)E * 4);
  int* srow   = (int*)alloc((size_t)E * 4);
  float* w    = (float*)alloc((size_t)E * 8 * 4);
  float* wo   = (float*)alloc((size_t)E * 4);

  float* out0 = (float*)d_out;
  float* outY = out0 + (size_t)N * 40;
  float* outZ = outY + (size_t)N * 128;

  const int nb = (N + 255) / 256;

  // CSR build (counting sort by row)
  hipMemsetAsync(deg, 0, (size_t)N * 4, stream);
  pack_watt<<<dim3((65536 + 255) / 256), dim3(256), 0, stream>>>(W_att, Bp);
  hist_deg<<<dim3((E + 255) / 256), dim3(256), 0, stream>>>(row, deg, E);
  scan1<<<dim3(nb), dim3(256), 0, stream>>>(deg, rp, bsum, N);
  scan2<<<dim3(1), dim3(256), 0, stream>>>(bsum, nb);
  scan3<<<dim3(nb), dim3(256), 0, stream>>>(rp, bsum, N, E);
  hipMemsetAsync(deg, 0, (size_t)N * 4, stream);  // reuse as cursor
  scatter_edges<<<dim3((E + 255) / 256), dim3(256), 0, stream>>>(row, col, rp, deg, scol, srow, E);

  // layer 1: H = x @ W_att(all heads)
  gemm_k256<256, 256, 8><<<dim3((N + 7) / 8), dim3(256), 0, stream>>>(x, Bp, nullptr, bufA, N);
  calc_s12<<<dim3((N * 8 + 255) / 256), dim3(256), 0, stream>>>(bufA, a1, a2, s1, s2, N);
  edge_w<<<dim3((E * 8 + 255) / 256), dim3(256), 0, stream>>>(srow, scol, s1, s2, w, E);
  agg_att<<<dim3(N), dim3(64), 0, stream>>>(bufA, w, rp, scol, h1, N);

  // GraphConv
  gemm_k256<256, 256, 8><<<dim3((N + 7) / 8), dim3(256), 0, stream>>>(h1, W_gc, nullptr, bufA, N);
  agg_gc<<<dim3(N), dim3(64), 0, stream>>>(bufA, rp, scol, b_gc, h2, N);

  // output head
  gemm_k256<40, 64, 8><<<dim3((N + 7) / 8), dim3(64), 0, stream>>>(h2, W_out, nullptr, Ho, N);
  calc_s12_out<<<dim3((N + 255) / 256), dim3(256), 0, stream>>>(Ho, a1_out, a2_out, s1o, s2o, N);
  edge_wo<<<dim3((E + 255) / 256), dim3(256), 0, stream>>>(srow, scol, s1o, s2o, wo, E);
  agg_out_lsm<<<dim3(N), dim3(64), 0, stream>>>(Ho, wo, rp, scol, out0, N);

  // y, z
  gemm_k256<128, 128, 8><<<dim3((N + 7) / 8), dim3(128), 0, stream>>>(h1, W_enc, b_enc, outY, N);
  gemm_k256<128, 128, 8><<<dim3((N + 7) / 8), dim3(128), 0, stream>>>(h2, W_enc, b_enc, outZ, N);
}

// Round 4
// 613.809 us; speedup vs baseline: 1.7018x; 1.5324x over previous
//
#include <hip/hip_runtime.h>
#include <math.h>

// N=50000, E=800000, nfeat=256, hid=256, nclass=40, nstruc=128, heads=8
typedef __attribute__((ext_vector_type(8))) short short8;
typedef __attribute__((ext_vector_type(8))) __bf16 bf16x8;
typedef __attribute__((ext_vector_type(4))) float f32x4;

__device__ inline ushort f2bf(float x) {
  union { float f; unsigned u; } v; v.f = x;
  unsigned r = v.u + 0x7fff + ((v.u >> 16) & 1);
  return (ushort)(r >> 16);
}
__device__ inline float bf2f(ushort b) {
  union { unsigned u; float f; } v; v.u = (unsigned)b << 16; return v.f;
}

// ---------------- pack weights into MFMA fragment order (hi/lo split bf16) ----------------
// frag order: off = ((kb*(Fp/16)+nb)*64 + lane)*8 + j ; lane=(kr>>3)*16|(n&15), j=kr&7
template <int F, int Fp>
__global__ void pack_b(const float* __restrict__ B, ushort* __restrict__ hi,
                       ushort* __restrict__ lo) {
  int tid = blockIdx.x * blockDim.x + threadIdx.x;
  if (tid >= 256 * Fp) return;
  int k = tid / Fp, n = tid % Fp;
  float val = (n < F) ? B[k * F + n] : 0.f;
  ushort h = f2bf(val);
  ushort l = f2bf(val - bf2f(h));
  int kb = k >> 5, kr = k & 31;
  int lane = ((kr >> 3) << 4) | (n & 15);
  int j = kr & 7;
  int nb = n >> 4;
  size_t off = ((size_t)(kb * (Fp / 16) + nb) * 64 + lane) * 8 + j;
  hi[off] = h; lo[off] = l;
}

// W_att [8][256][32] -> logical B[k][n], n = h*32+j2
__global__ void pack_watt_frag(const float* __restrict__ W_att, ushort* __restrict__ hi,
                               ushort* __restrict__ lo) {
  int tid = blockIdx.x * blockDim.x + threadIdx.x;
  if (tid >= 256 * 256) return;
  int k = tid >> 8, n = tid & 255;
  float val = W_att[(size_t)(n >> 5) * 8192 + k * 32 + (n & 31)];
  ushort h = f2bf(val);
  ushort l = f2bf(val - bf2f(h));
  int kb = k >> 5, kr = k & 31;
  int lane = ((kr >> 3) << 4) | (n & 15);
  int j = kr & 7;
  int nb = n >> 4;
  size_t off = ((size_t)(kb * 16 + nb) * 64 + lane) * 8 + j;
  hi[off] = h; lo[off] = l;
}

// ---------------- split-bf16 MFMA GEMM: C[N,F] = A[N,256] @ B[256,F] (+bias) ----------------
// BM=64 rows/block, full width per block; 4 waves, wave w covers cols [w*Fp/4, ...)
template <int Fp, int F, bool BIAS>
__global__ __launch_bounds__(256) void gemm_mfma(const float* __restrict__ A,
                                                 const ushort* __restrict__ Bhi,
                                                 const ushort* __restrict__ Blo,
                                                 const float* __restrict__ bias,
                                                 float* __restrict__ C, int N) {
  constexpr int NB = Fp / 64;  // 16-col fragments per wave
  __shared__ ushort lhs_hi[64 * 256];
  __shared__ ushort lhs_lo[64 * 256];
  int n0 = blockIdx.x * 64;
  int t = threadIdx.x;
  // ---- stage A tile (64x256 f32 -> hi/lo bf16, XOR-swizzled 16B units) ----
  {
    int r = t >> 2, q = t & 3;
    bool rin = (n0 + r) < N;
    const float* arow = A + (size_t)(n0 + r) * 256;
#pragma unroll
    for (int i = 0; i < 8; ++i) {
      int c0 = q * 64 + i * 8;
      float4 f0 = {0.f, 0.f, 0.f, 0.f}, f1 = {0.f, 0.f, 0.f, 0.f};
      if (rin) {
        f0 = *reinterpret_cast<const float4*>(arow + c0);
        f1 = *reinterpret_cast<const float4*>(arow + c0 + 4);
      }
      float ff[8] = {f0.x, f0.y, f0.z, f0.w, f1.x, f1.y, f1.z, f1.w};
      short8 sh, sl;
#pragma unroll
      for (int j = 0; j < 8; ++j) {
        ushort hh = f2bf(ff[j]);
        sh[j] = (short)hh;
        sl[j] = (short)f2bf(ff[j] - bf2f(hh));
      }
      int c8 = (c0 >> 3) ^ (r & 7);
      *reinterpret_cast<short8*>(&lhs_hi[r * 256 + c8 * 8]) = sh;
      *reinterpret_cast<short8*>(&lhs_lo[r * 256 + c8 * 8]) = sl;
    }
  }
  __syncthreads();
  // ---- compute ----
  int w = t >> 6, l = t & 63;
  int lr = l & 15, lk = l >> 4;
  f32x4 acc[4][NB];
#pragma unroll
  for (int m = 0; m < 4; ++m)
#pragma unroll
    for (int nb = 0; nb < NB; ++nb) acc[m][nb] = (f32x4){0.f, 0.f, 0.f, 0.f};

  for (int ks = 0; ks < 8; ++ks) {
    bf16x8 ah[4], al[4];
#pragma unroll
    for (int m = 0; m < 4; ++m) {
      int row = m * 16 + lr;
      int c8 = (ks * 4 + lk) ^ (row & 7);
      ah[m] = *reinterpret_cast<const bf16x8*>(&lhs_hi[row * 256 + c8 * 8]);
      al[m] = *reinterpret_cast<const bf16x8*>(&lhs_lo[row * 256 + c8 * 8]);
    }
    bf16x8 bh[NB], bl[NB];
#pragma unroll
    for (int nb = 0; nb < NB; ++nb) {
      size_t off = ((size_t)(ks * (Fp / 16) + w * NB + nb) * 64 + l) * 8;
      bh[nb] = *reinterpret_cast<const bf16x8*>(&Bhi[off]);
      bl[nb] = *reinterpret_cast<const bf16x8*>(&Blo[off]);
    }
#pragma unroll
    for (int m = 0; m < 4; ++m)
#pragma unroll
      for (int nb = 0; nb < NB; ++nb) {
        acc[m][nb] = __builtin_amdgcn_mfma_f32_16x16x32_bf16(ah[m], bh[nb], acc[m][nb], 0, 0, 0);
        acc[m][nb] = __builtin_amdgcn_mfma_f32_16x16x32_bf16(ah[m], bl[nb], acc[m][nb], 0, 0, 0);
        acc[m][nb] = __builtin_amdgcn_mfma_f32_16x16x32_bf16(al[m], bh[nb], acc[m][nb], 0, 0, 0);
      }
  }
  // ---- write C: col=lane&15, row=(lane>>4)*4+reg ----
#pragma unroll
  for (int m = 0; m < 4; ++m) {
    int row = n0 + m * 16 + lk * 4;
#pragma unroll
    for (int nb = 0; nb < NB; ++nb) {
      int col = w * (NB * 16) + nb * 16 + lr;
      if (col < F) {
        float bi = BIAS ? bias[col] : 0.f;
#pragma unroll
        for (int rg = 0; rg < 4; ++rg) {
          if (row + rg < N) C[(size_t)(row + rg) * F + col] = acc[m][nb][rg] + bi;
        }
      }
    }
  }
}

// ---------------- s1/s2 per node per head ----------------
__global__ void calc_s12(const float* __restrict__ H, const float* __restrict__ a1,
                         const float* __restrict__ a2, float* __restrict__ s1,
                         float* __restrict__ s2, int N) {
  int tid = blockIdx.x * blockDim.x + threadIdx.x;
  if (tid >= N * 8) return;
  int h = tid & 7;
  int n = tid >> 3;
  const float* hp = H + (size_t)n * 256 + h * 32;
  const float* A1 = a1 + h * 32;
  const float* A2 = a2 + h * 32;
  float d1 = 0.f, d2 = 0.f;
#pragma unroll
  for (int j = 0; j < 32; ++j) {
    float v = hp[j];
    d1 = fmaf(v, A1[j], d1);
    d2 = fmaf(v, A2[j], d2);
  }
  s1[tid] = d1;
  s2[tid] = d2;
}

__global__ void calc_s12_out(const float* __restrict__ Ho, const float* __restrict__ a1o,
                             const float* __restrict__ a2o, float* __restrict__ s1o,
                             float* __restrict__ s2o, int N) {
  int n = blockIdx.x * blockDim.x + threadIdx.x;
  if (n >= N) return;
  const float* hp = Ho + (size_t)n * 40;
  float d1 = 0.f, d2 = 0.f;
#pragma unroll
  for (int j = 0; j < 40; ++j) {
    float v = hp[j];
    d1 = fmaf(v, a1o[j], d1);
    d2 = fmaf(v, a2o[j], d2);
  }
  s1o[n] = d1;
  s2o[n] = d2;
}

// ---------------- CSR build ----------------
__global__ void hist_deg(const int* __restrict__ row, int* __restrict__ deg, int E) {
  int e = blockIdx.x * blockDim.x + threadIdx.x;
  if (e < E) atomicAdd(&deg[row[e]], 1);
}

__global__ void scan1(const int* __restrict__ deg, int* __restrict__ rp, int* __restrict__ bsum,
                      int N) {
  __shared__ int sd[256];
  int t = threadIdx.x;
  int i = blockIdx.x * 256 + t;
  int v = (i < N) ? deg[i] : 0;
  sd[t] = v;
  __syncthreads();
  for (int off = 1; off < 256; off <<= 1) {
    int x = (t >= off) ? sd[t - off] : 0;
    __syncthreads();
    sd[t] += x;
    __syncthreads();
  }
  if (i < N) rp[i] = sd[t] - v;
  if (t == 255) bsum[blockIdx.x] = sd[255];
}

__global__ void scan2(int* __restrict__ bsum, int nb) {
  __shared__ int sd[256];
  int t = threadIdx.x;
  int v = (t < nb) ? bsum[t] : 0;
  sd[t] = v;
  __syncthreads();
  for (int off = 1; off < 256; off <<= 1) {
    int x = (t >= off) ? sd[t - off] : 0;
    __syncthreads();
    sd[t] += x;
    __syncthreads();
  }
  if (t < nb) bsum[t] = sd[t] - v;
}

__global__ void scan3(int* __restrict__ rp, const int* __restrict__ bsum, int N, int E) {
  int i = blockIdx.x * 256 + threadIdx.x;
  if (i < N) rp[i] += bsum[blockIdx.x];
  if (i == 0) rp[N] = E;
}

__global__ void scatter_edges(const int* __restrict__ row, const int* __restrict__ col,
                              const int* __restrict__ rp, int* __restrict__ cur,
                              int* __restrict__ scol, int* __restrict__ srow, int E) {
  int e = blockIdx.x * blockDim.x + threadIdx.x;
  if (e >= E) return;
  int r = row[e];
  int p = atomicAdd(&cur[r], 1);
  int idx = rp[r] + p;
  scol[idx] = col[e];
  srow[idx] = r;
}

// ---------------- edge weights ----------------
__global__ void edge_w(const int* __restrict__ srow, const int* __restrict__ scol,
                       const float* __restrict__ s1, const float* __restrict__ s2,
                       float* __restrict__ w, int E) {
  int tid = blockIdx.x * blockDim.x + threadIdx.x;
  if (tid >= E * 8) return;
  int e = tid >> 3, h = tid & 7;
  int r = srow[e], c = scol[e];
  float lg = s1[r * 8 + h] + s2[c * 8 + h];
  float lr = lg > 0.f ? lg : 0.2f * lg;
  w[tid] = expf(-lr);
}

__global__ void edge_wo(const int* __restrict__ srow, const int* __restrict__ scol,
                        const float* __restrict__ s1o, const float* __restrict__ s2o,
                        float* __restrict__ wo, int E) {
  int e = blockIdx.x * blockDim.x + threadIdx.x;
  if (e >= E) return;
  float lg = s1o[srow[e]] + s2o[scol[e]];
  float lr = lg > 0.f ? lg : 0.2f * lg;
  wo[e] = expf(-lr);
}

// ---------------- GAT layer-1 aggregation: one wave/node, float4/lane ----------------
__global__ __launch_bounds__(64) void agg_att(const float* __restrict__ H,
                                              const float* __restrict__ w,
                                              const int* __restrict__ rp,
                                              const int* __restrict__ scol,
                                              float* __restrict__ h1, int N) {
  int n = blockIdx.x;
  int t = threadIdx.x;
  int head = t >> 3;
  float4 acc = {0.f, 0.f, 0.f, 0.f};
  float rs = 0.f;
  int beg = rp[n], end = rp[n + 1];
  for (int i = beg; i < end; ++i) {
    int c = scol[i];
    float wv = w[i * 8 + head];
    rs += wv;
    const float4 hv = *reinterpret_cast<const float4*>(H + (size_t)c * 256 + t * 4);
    acc.x = fmaf(wv, hv.x, acc.x);
    acc.y = fmaf(wv, hv.y, acc.y);
    acc.z = fmaf(wv, hv.z, acc.z);
    acc.w = fmaf(wv, hv.w, acc.w);
  }
  float inv = 1.f / (rs + 1e-16f);
  float4 o;
  o.x = acc.x * inv; o.y = acc.y * inv; o.z = acc.z * inv; o.w = acc.w * inv;
  o.x = o.x > 0.f ? o.x : expm1f(o.x);
  o.y = o.y > 0.f ? o.y : expm1f(o.y);
  o.z = o.z > 0.f ? o.z : expm1f(o.z);
  o.w = o.w > 0.f ? o.w : expm1f(o.w);
  *reinterpret_cast<float4*>(h1 + (size_t)n * 256 + t * 4) = o;
}

// ---------------- GraphConv aggregation ----------------
__global__ __launch_bounds__(64) void agg_gc(const float* __restrict__ S,
                                             const int* __restrict__ rp,
                                             const int* __restrict__ scol,
                                             const float* __restrict__ b_gc,
                                             float* __restrict__ h2, int N) {
  int n = blockIdx.x;
  int t = threadIdx.x;
  float4 acc = {0.f, 0.f, 0.f, 0.f};
  int beg = rp[n], end = rp[n + 1];
  for (int i = beg; i < end; ++i) {
    int c = scol[i];
    const float4 sv = *reinterpret_cast<const float4*>(S + (size_t)c * 256 + t * 4);
    acc.x += sv.x; acc.y += sv.y; acc.z += sv.z; acc.w += sv.w;
  }
  const float4 bv = *reinterpret_cast<const float4*>(b_gc + t * 4);
  float4 o = {acc.x + bv.x, acc.y + bv.y, acc.z + bv.z, acc.w + bv.w};
  *reinterpret_cast<float4*>(h2 + (size_t)n * 256 + t * 4) = o;
}

// ---------------- output head aggregation + elu + log_softmax ----------------
__global__ __launch_bounds__(64) void agg_out_lsm(const float* __restrict__ Ho,
                                                  const float* __restrict__ wo,
                                                  const int* __restrict__ rp,
                                                  const int* __restrict__ scol,
                                                  float* __restrict__ out0, int N) {
  int n = blockIdx.x;
  int t = threadIdx.x;
  float acc = 0.f, rs = 0.f;
  int beg = rp[n], end = rp[n + 1];
  for (int i = beg; i < end; ++i) {
    int c = scol[i];
    float wv = wo[i];
    rs += wv;
    if (t < 40) acc = fmaf(wv, Ho[(size_t)c * 40 + t], acc);
  }
  float hp = acc / (rs + 1e-16f);
  float xo = (t < 40) ? (hp > 0.f ? hp : expm1f(hp)) : -3.0e38f;
  float mx = xo;
#pragma unroll
  for (int m = 1; m < 64; m <<= 1) mx = fmaxf(mx, __shfl_xor(mx, m));
  float ex = (t < 40) ? expf(xo - mx) : 0.f;
  float sum = ex;
#pragma unroll
  for (int m = 1; m < 64; m <<= 1) sum += __shfl_xor(sum, m);
  if (t < 40) out0[(size_t)n * 40 + t] = xo - mx - logf(sum);
}

// ---------------- launch ----------------
extern "C" void kernel_launch(void* const* d_in, const int* in_sizes, int n_in,
                              void* d_out, int out_size, void* d_ws, size_t ws_size,
                              hipStream_t stream) {
  const float* x      = (const float*)d_in[0];
  const int*   ei     = (const int*)d_in[1];
  const float* W_att  = (const float*)d_in[2];
  const float* a1     = (const float*)d_in[3];
  const float* a2     = (const float*)d_in[4];
  const float* W_out  = (const float*)d_in[5];
  const float* a1_out = (const float*)d_in[6];
  const float* a2_out = (const float*)d_in[7];
  const float* W_gc   = (const float*)d_in[8];
  const float* b_gc   = (const float*)d_in[9];
  const float* W_enc  = (const float*)d_in[10];
  const float* b_enc  = (const float*)d_in[11];

  const int N = in_sizes[0] / 256;
  const int E = in_sizes[1] / 2;
  const int* row = ei;
  const int* col = ei + E;

  char* p = (char*)d_ws;
  auto alloc = [&](size_t bytes) -> void* {
    void* r = (void*)p;
    p += (bytes + 255) & ~(size_t)255;
    return r;
  };
  float* bufA = (float*)alloc((size_t)N * 256 * 4);  // H, later support
  float* h1   = (float*)alloc((size_t)N * 256 * 4);
  float* h2   = (float*)alloc((size_t)N * 256 * 4);
  float* Ho   = (float*)alloc((size_t)N * 40 * 4);
  float* s1   = (float*)alloc((size_t)N * 8 * 4);
  float* s2   = (float*)alloc((size_t)N * 8 * 4);
  float* s1o  = (float*)alloc((size_t)N * 4);
  float* s2o  = (float*)alloc((size_t)N * 4);
  int* deg    = (int*)alloc((size_t)N * 4);
  int* rp     = (int*)alloc((size_t)(N + 1) * 4);
  int* bsum   = (int*)alloc(256 * 4);
  int* scol   = (int*)alloc((size_t)E * 4);
  int* srow   = (int*)alloc((size_t)E * 4);
  float* w    = (float*)alloc((size_t)E * 8 * 4);
  float* wo   = (float*)alloc((size_t)E * 4);
  ushort* BpH = (ushort*)alloc((size_t)65536 * 2);
  ushort* BpL = (ushort*)alloc((size_t)65536 * 2);
  ushort* WgH = (ushort*)alloc((size_t)65536 * 2);
  ushort* WgL = (ushort*)alloc((size_t)65536 * 2);
  ushort* WeH = (ushort*)alloc((size_t)32768 * 2);
  ushort* WeL = (ushort*)alloc((size_t)32768 * 2);
  ushort* WoH = (ushort*)alloc((size_t)16384 * 2);
  ushort* WoL = (ushort*)alloc((size_t)16384 * 2);

  float* out0 = (float*)d_out;
  float* outY = out0 + (size_t)N * 40;
  float* outZ = outY + (size_t)N * 128;

  const int nb = (N + 255) / 256;
  const int gblk = (N + 63) / 64;

  // weight packing
  pack_watt_frag<<<dim3(256), dim3(256), 0, stream>>>(W_att, BpH, BpL);
  pack_b<256, 256><<<dim3(256), dim3(256), 0, stream>>>(W_gc, WgH, WgL);
  pack_b<128, 128><<<dim3(128), dim3(256), 0, stream>>>(W_enc, WeH, WeL);
  pack_b<40, 64><<<dim3(64), dim3(256), 0, stream>>>(W_out, WoH, WoL);

  // CSR build (counting sort by row)
  hipMemsetAsync(deg, 0, (size_t)N * 4, stream);
  hist_deg<<<dim3((E + 255) / 256), dim3(256), 0, stream>>>(row, deg, E);
  scan1<<<dim3(nb), dim3(256), 0, stream>>>(deg, rp, bsum, N);
  scan2<<<dim3(1), dim3(256), 0, stream>>>(bsum, nb);
  scan3<<<dim3(nb), dim3(256), 0, stream>>>(rp, bsum, N, E);
  hipMemsetAsync(deg, 0, (size_t)N * 4, stream);  // reuse as cursor
  scatter_edges<<<dim3((E + 255) / 256), dim3(256), 0, stream>>>(row, col, rp, deg, scol, srow, E);

  // layer 1: H = x @ W_att(all heads)
  gemm_mfma<256, 256, false><<<dim3(gblk), dim3(256), 0, stream>>>(x, BpH, BpL, nullptr, bufA, N);
  calc_s12<<<dim3((N * 8 + 255) / 256), dim3(256), 0, stream>>>(bufA, a1, a2, s1, s2, N);
  edge_w<<<dim3((E * 8 + 255) / 256), dim3(256), 0, stream>>>(srow, scol, s1, s2, w, E);
  agg_att<<<dim3(N), dim3(64), 0, stream>>>(bufA, w, rp, scol, h1, N);

  // GraphConv
  gemm_mfma<256, 256, false><<<dim3(gblk), dim3(256), 0, stream>>>(h1, WgH, WgL, nullptr, bufA, N);
  agg_gc<<<dim3(N), dim3(64), 0, stream>>>(bufA, rp, scol, b_gc, h2, N);

  // output head
  gemm_mfma<64, 40, false><<<dim3(gblk), dim3(256), 0, stream>>>(h2, WoH, WoL, nullptr, Ho, N);
  calc_s12_out<<<dim3((N + 255) / 256), dim3(256), 0, stream>>>(Ho, a1_out, a2_out, s1o, s2o, N);
  edge_wo<<<dim3((E + 255) / 256), dim3(256), 0, stream>>>(srow, scol, s1o, s2o, wo, E);
  agg_out_lsm<<<dim3(N), dim3(64), 0, stream>>>(Ho, wo, rp, scol, out0, N);

  // y, z
  gemm_mfma<128, 128, true><<<dim3(gblk), dim3(256), 0, stream>>>(h1, WeH, WeL, b_enc, outY, N);
  gemm_mfma<128, 128, true><<<dim3(gblk), dim3(256), 0, stream>>>(h2, WeH, WeL, b_enc, outZ, N);
}

// Round 8
// 511.115 us; speedup vs baseline: 2.0438x; 1.2009x over previous
//
#include <hip/hip_runtime.h>
#include <math.h>

// N=50000, E=800000, nfeat=256, hid=256, nclass=40, nstruc=128, heads=8
typedef __attribute__((ext_vector_type(8))) short short8;
typedef __attribute__((ext_vector_type(4))) ushort u16x4;
typedef __attribute__((ext_vector_type(8))) __bf16 bf16x8;
typedef __attribute__((ext_vector_type(4))) float f32x4;

__device__ inline ushort f2bf(float x) {
  union { float f; unsigned u; } v; v.f = x;
  unsigned r = v.u + 0x7fff + ((v.u >> 16) & 1);
  return (ushort)(r >> 16);
}
__device__ inline float bf2f(ushort b) {
  union { unsigned u; float f; } v; v.u = (unsigned)b << 16; return v.f;
}

// ---------------- pack weights into MFMA fragment order (hi/lo split bf16) ----------------
// frag order: off = ((kb*(Fp/16)+nb)*64 + lane)*8 + j ; lane=(kr>>3)*16|(n&15), j=kr&7
template <int F, int Fp>
__global__ void pack_b(const float* __restrict__ B, ushort* __restrict__ hi,
                       ushort* __restrict__ lo) {
  int tid = blockIdx.x * blockDim.x + threadIdx.x;
  if (tid >= 256 * Fp) return;
  int k = tid / Fp, n = tid % Fp;
  float val = (n < F) ? B[k * F + n] : 0.f;
  ushort h = f2bf(val);
  ushort l = f2bf(val - bf2f(h));
  int kb = k >> 5, kr = k & 31;
  int lane = ((kr >> 3) << 4) | (n & 15);
  int j = kr & 7;
  int nb = n >> 4;
  size_t off = ((size_t)(kb * (Fp / 16) + nb) * 64 + lane) * 8 + j;
  hi[off] = h; lo[off] = l;
}

// W_att [8][256][32] -> logical B[k][n], n = h*32+j2
__global__ void pack_watt_frag(const float* __restrict__ W_att, ushort* __restrict__ hi,
                               ushort* __restrict__ lo) {
  int tid = blockIdx.x * blockDim.x + threadIdx.x;
  if (tid >= 256 * 256) return;
  int k = tid >> 8, n = tid & 255;
  float val = W_att[(size_t)(n >> 5) * 8192 + k * 32 + (n & 31)];
  ushort h = f2bf(val);
  ushort l = f2bf(val - bf2f(h));
  int kb = k >> 5, kr = k & 31;
  int lane = ((kr >> 3) << 4) | (n & 15);
  int j = kr & 7;
  int nb = n >> 4;
  size_t off = ((size_t)(kb * 16 + nb) * 64 + lane) * 8 + j;
  hi[off] = h; lo[off] = l;
}

// ---------------- split-bf16 MFMA GEMM: C[N,F] = A[N,256] @ B[256,F] (+bias) ----------------
// OUTMODE: 0 = f32 only, 1 = f32 + bf16 copy, 2 = bf16 only
template <int Fp, int F, int OUTMODE, bool BIAS>
__global__ __launch_bounds__(256) void gemm_mfma(const float* __restrict__ A,
                                                 const ushort* __restrict__ Bhi,
                                                 const ushort* __restrict__ Blo,
                                                 const float* __restrict__ bias,
                                                 float* __restrict__ C,
                                                 ushort* __restrict__ Cb, int N) {
  constexpr int NB = Fp / 64;  // 16-col fragments per wave
  __shared__ ushort lhs_hi[64 * 256];
  __shared__ ushort lhs_lo[64 * 256];
  int n0 = blockIdx.x * 64;
  int t = threadIdx.x;
  // ---- stage A tile (64x256 f32 -> hi/lo bf16, XOR-swizzled 16B units) ----
  {
    int r = t >> 2, q = t & 3;
    bool rin = (n0 + r) < N;
    const float* arow = A + (size_t)(n0 + r) * 256;
#pragma unroll
    for (int i = 0; i < 8; ++i) {
      int c0 = q * 64 + i * 8;
      float4 f0 = {0.f, 0.f, 0.f, 0.f}, f1 = {0.f, 0.f, 0.f, 0.f};
      if (rin) {
        f0 = *reinterpret_cast<const float4*>(arow + c0);
        f1 = *reinterpret_cast<const float4*>(arow + c0 + 4);
      }
      float ff[8] = {f0.x, f0.y, f0.z, f0.w, f1.x, f1.y, f1.z, f1.w};
      short8 sh, sl;
#pragma unroll
      for (int j = 0; j < 8; ++j) {
        ushort hh = f2bf(ff[j]);
        sh[j] = (short)hh;
        sl[j] = (short)f2bf(ff[j] - bf2f(hh));
      }
      int c8 = (c0 >> 3) ^ (r & 7);
      *reinterpret_cast<short8*>(&lhs_hi[r * 256 + c8 * 8]) = sh;
      *reinterpret_cast<short8*>(&lhs_lo[r * 256 + c8 * 8]) = sl;
    }
  }
  __syncthreads();
  // ---- compute ----
  int w = t >> 6, l = t & 63;
  int lr = l & 15, lk = l >> 4;
  f32x4 acc[4][NB];
#pragma unroll
  for (int m = 0; m < 4; ++m)
#pragma unroll
    for (int nb = 0; nb < NB; ++nb) acc[m][nb] = (f32x4){0.f, 0.f, 0.f, 0.f};

  for (int ks = 0; ks < 8; ++ks) {
    bf16x8 ah[4], al[4];
#pragma unroll
    for (int m = 0; m < 4; ++m) {
      int row = m * 16 + lr;
      int c8 = (ks * 4 + lk) ^ (row & 7);
      ah[m] = *reinterpret_cast<const bf16x8*>(&lhs_hi[row * 256 + c8 * 8]);
      al[m] = *reinterpret_cast<const bf16x8*>(&lhs_lo[row * 256 + c8 * 8]);
    }
    bf16x8 bh[NB], bl[NB];
#pragma unroll
    for (int nb = 0; nb < NB; ++nb) {
      size_t off = ((size_t)(ks * (Fp / 16) + w * NB + nb) * 64 + l) * 8;
      bh[nb] = *reinterpret_cast<const bf16x8*>(&Bhi[off]);
      bl[nb] = *reinterpret_cast<const bf16x8*>(&Blo[off]);
    }
#pragma unroll
    for (int m = 0; m < 4; ++m)
#pragma unroll
      for (int nb = 0; nb < NB; ++nb) {
        acc[m][nb] = __builtin_amdgcn_mfma_f32_16x16x32_bf16(ah[m], bh[nb], acc[m][nb], 0, 0, 0);
        acc[m][nb] = __builtin_amdgcn_mfma_f32_16x16x32_bf16(ah[m], bl[nb], acc[m][nb], 0, 0, 0);
        acc[m][nb] = __builtin_amdgcn_mfma_f32_16x16x32_bf16(al[m], bh[nb], acc[m][nb], 0, 0, 0);
      }
  }
  // ---- write C: col=lane&15, row=(lane>>4)*4+reg ----
#pragma unroll
  for (int m = 0; m < 4; ++m) {
    int row = n0 + m * 16 + lk * 4;
#pragma unroll
    for (int nb = 0; nb < NB; ++nb) {
      int col = w * (NB * 16) + nb * 16 + lr;
      if (col < F) {
        float bi = BIAS ? bias[col] : 0.f;
#pragma unroll
        for (int rg = 0; rg < 4; ++rg) {
          if (row + rg < N) {
            float v = acc[m][nb][rg] + bi;
            if (OUTMODE != 2) C[(size_t)(row + rg) * F + col] = v;
            if (OUTMODE != 0) Cb[(size_t)(row + rg) * F + col] = f2bf(v);
          }
        }
      }
    }
  }
}

// ---------------- s1/s2 per node per head ----------------
__global__ void calc_s12(const float* __restrict__ H, const float* __restrict__ a1,
                         const float* __restrict__ a2, float* __restrict__ s1,
                         float* __restrict__ s2, int N) {
  int tid = blockIdx.x * blockDim.x + threadIdx.x;
  if (tid >= N * 8) return;
  int h = tid & 7;
  int n = tid >> 3;
  const float* hp = H + (size_t)n * 256 + h * 32;
  const float* A1 = a1 + h * 32;
  const float* A2 = a2 + h * 32;
  float d1 = 0.f, d2 = 0.f;
#pragma unroll
  for (int j = 0; j < 32; ++j) {
    float v = hp[j];
    d1 = fmaf(v, A1[j], d1);
    d2 = fmaf(v, A2[j], d2);
  }
  s1[tid] = d1;
  s2[tid] = d2;
}

__global__ void calc_s12_out(const float* __restrict__ Ho, const float* __restrict__ a1o,
                             const float* __restrict__ a2o, float* __restrict__ s1o,
                             float* __restrict__ s2o, int N) {
  int n = blockIdx.x * blockDim.x + threadIdx.x;
  if (n >= N) return;
  const float* hp = Ho + (size_t)n * 40;
  float d1 = 0.f, d2 = 0.f;
#pragma unroll
  for (int j = 0; j < 40; ++j) {
    float v = hp[j];
    d1 = fmaf(v, a1o[j], d1);
    d2 = fmaf(v, a2o[j], d2);
  }
  s1o[n] = d1;
  s2o[n] = d2;
}

// ---------------- CSR build ----------------
__global__ void hist_deg(const int* __restrict__ row, int* __restrict__ deg, int E) {
  int e = blockIdx.x * blockDim.x + threadIdx.x;
  if (e < E) atomicAdd(&deg[row[e]], 1);
}

__global__ void scan1(const int* __restrict__ deg, int* __restrict__ rp, int* __restrict__ bsum,
                      int N) {
  __shared__ int sd[256];
  int t = threadIdx.x;
  int i = blockIdx.x * 256 + t;
  int v = (i < N) ? deg[i] : 0;
  sd[t] = v;
  __syncthreads();
  for (int off = 1; off < 256; off <<= 1) {
    int x = (t >= off) ? sd[t - off] : 0;
    __syncthreads();
    sd[t] += x;
    __syncthreads();
  }
  if (i < N) rp[i] = sd[t] - v;
  if (t == 255) bsum[blockIdx.x] = sd[255];
}

__global__ void scan2(int* __restrict__ bsum, int nb) {
  __shared__ int sd[256];
  int t = threadIdx.x;
  int v = (t < nb) ? bsum[t] : 0;
  sd[t] = v;
  __syncthreads();
  for (int off = 1; off < 256; off <<= 1) {
    int x = (t >= off) ? sd[t - off] : 0;
    __syncthreads();
    sd[t] += x;
    __syncthreads();
  }
  if (t < nb) bsum[t] = sd[t] - v;
}

__global__ void scan3(int* __restrict__ rp, const int* __restrict__ bsum, int N, int E) {
  int i = blockIdx.x * 256 + threadIdx.x;
  if (i < N) rp[i] += bsum[blockIdx.x];
  if (i == 0) rp[N] = E;
}

__global__ void scatter_edges(const int* __restrict__ row, const int* __restrict__ col,
                              const int* __restrict__ rp, int* __restrict__ cur,
                              int* __restrict__ scol, int* __restrict__ srow, int E) {
  int e = blockIdx.x * blockDim.x + threadIdx.x;
  if (e >= E) return;
  int r = row[e];
  int p = atomicAdd(&cur[r], 1);
  int idx = rp[r] + p;
  scol[idx] = col[e];
  srow[idx] = r;
}

// ---------------- edge weights ----------------
__global__ void edge_w(const int* __restrict__ srow, const int* __restrict__ scol,
                       const float* __restrict__ s1, const float* __restrict__ s2,
                       float* __restrict__ w, int E) {
  int tid = blockIdx.x * blockDim.x + threadIdx.x;
  if (tid >= E * 8) return;
  int e = tid >> 3, h = tid & 7;
  int r = srow[e], c = scol[e];
  float lg = s1[r * 8 + h] + s2[c * 8 + h];
  float lr = lg > 0.f ? lg : 0.2f * lg;
  w[tid] = expf(-lr);
}

__global__ void edge_wo(const int* __restrict__ srow, const int* __restrict__ scol,
                        const float* __restrict__ s1o, const float* __restrict__ s2o,
                        float* __restrict__ wo, int E) {
  int e = blockIdx.x * blockDim.x + threadIdx.x;
  if (e >= E) return;
  float lg = s1o[srow[e]] + s2o[scol[e]];
  float lr = lg > 0.f ? lg : 0.2f * lg;
  wo[e] = expf(-lr);
}

// ---------------- GAT layer-1 aggregation: one wave/node, 4 bf16/lane ----------------
__global__ __launch_bounds__(64) void agg_att(const ushort* __restrict__ Hb,
                                              const float* __restrict__ w,
                                              const int* __restrict__ rp,
                                              const int* __restrict__ scol,
                                              float* __restrict__ h1, int N) {
  int n = blockIdx.x;
  int t = threadIdx.x;          // features t*4..t*4+3 ; head = t>>3
  int head = t >> 3;
  float acc[4] = {0.f, 0.f, 0.f, 0.f};
  float rs = 0.f;
  int beg = rp[n], end = rp[n + 1];
  for (int i = beg; i < end; ++i) {
    int c = scol[i];
    float wv = w[i * 8 + head];
    rs += wv;
    const u16x4 hv = *reinterpret_cast<const u16x4*>(Hb + (size_t)c * 256 + t * 4);
#pragma unroll
    for (int j = 0; j < 4; ++j) acc[j] = fmaf(wv, bf2f(hv[j]), acc[j]);
  }
  float inv = 1.f / (rs + 1e-16f);
  float4 o;
  o.x = acc[0] * inv; o.y = acc[1] * inv; o.z = acc[2] * inv; o.w = acc[3] * inv;
  o.x = o.x > 0.f ? o.x : expm1f(o.x);
  o.y = o.y > 0.f ? o.y : expm1f(o.y);
  o.z = o.z > 0.f ? o.z : expm1f(o.z);
  o.w = o.w > 0.f ? o.w : expm1f(o.w);
  *reinterpret_cast<float4*>(h1 + (size_t)n * 256 + t * 4) = o;
}

// ---------------- GraphConv aggregation: one wave/node, 4 bf16/lane ----------------
__global__ __launch_bounds__(64) void agg_gc(const ushort* __restrict__ Sb,
                                             const int* __restrict__ rp,
                                             const int* __restrict__ scol,
                                             const float* __restrict__ b_gc,
                                             float* __restrict__ h2, int N) {
  int n = blockIdx.x;
  int t = threadIdx.x;
  float acc[4] = {0.f, 0.f, 0.f, 0.f};
  int beg = rp[n], end = rp[n + 1];
  for (int i = beg; i < end; ++i) {
    int c = scol[i];
    const u16x4 sv = *reinterpret_cast<const u16x4*>(Sb + (size_t)c * 256 + t * 4);
#pragma unroll
    for (int j = 0; j < 4; ++j) acc[j] += bf2f(sv[j]);
  }
  const float4 bv = *reinterpret_cast<const float4*>(b_gc + t * 4);
  float4 o = {acc[0] + bv.x, acc[1] + bv.y, acc[2] + bv.z, acc[3] + bv.w};
  *reinterpret_cast<float4*>(h2 + (size_t)n * 256 + t * 4) = o;
}

// ---------------- output head aggregation + elu + log_softmax ----------------
__global__ __launch_bounds__(64) void agg_out_lsm(const float* __restrict__ Ho,
                                                  const float* __restrict__ wo,
                                                  const int* __restrict__ rp,
                                                  const int* __restrict__ scol,
                                                  float* __restrict__ out0, int N) {
  int n = blockIdx.x;
  int t = threadIdx.x;
  float acc = 0.f, rs = 0.f;
  int beg = rp[n], end = rp[n + 1];
  for (int i = beg; i < end; ++i) {
    int c = scol[i];
    float wv = wo[i];
    rs += wv;
    if (t < 40) acc = fmaf(wv, Ho[(size_t)c * 40 + t], acc);
  }
  float hp = acc / (rs + 1e-16f);
  float xo = (t < 40) ? (hp > 0.f ? hp : expm1f(hp)) : -3.0e38f;
  float mx = xo;
#pragma unroll
  for (int m = 1; m < 64; m <<= 1) mx = fmaxf(mx, __shfl_xor(mx, m));
  float ex = (t < 40) ? expf(xo - mx) : 0.f;
  float sum = ex;
#pragma unroll
  for (int m = 1; m < 64; m <<= 1) sum += __shfl_xor(sum, m);
  if (t < 40) out0[(size_t)n * 40 + t] = xo - mx - logf(sum);
}

// ---------------- launch ----------------
extern "C" void kernel_launch(void* const* d_in, const int* in_sizes, int n_in,
                              void* d_out, int out_size, void* d_ws, size_t ws_size,
                              hipStream_t stream) {
  const float* x      = (const float*)d_in[0];
  const int*   ei     = (const int*)d_in[1];
  const float* W_att  = (const float*)d_in[2];
  const float* a1     = (const float*)d_in[3];
  const float* a2     = (const float*)d_in[4];
  const float* W_out  = (const float*)d_in[5];
  const float* a1_out = (const float*)d_in[6];
  const float* a2_out = (const float*)d_in[7];
  const float* W_gc   = (const float*)d_in[8];
  const float* b_gc   = (const float*)d_in[9];
  const float* W_enc  = (const float*)d_in[10];
  const float* b_enc  = (const float*)d_in[11];

  const int N = in_sizes[0] / 256;
  const int E = in_sizes[1] / 2;
  const int* row = ei;
  const int* col = ei + E;

  char* p = (char*)d_ws;
  auto alloc = [&](size_t bytes) -> void* {
    void* r = (void*)p;
    p += (bytes + 255) & ~(size_t)255;
    return r;
  };
  float* bufA = (float*)alloc((size_t)N * 256 * 4);  // H f32 (layer1)
  ushort* hbuf = (ushort*)alloc((size_t)N * 256 * 2);  // bf16 gather buf (H, then support)
  float* h1   = (float*)alloc((size_t)N * 256 * 4);
  float* h2   = (float*)alloc((size_t)N * 256 * 4);
  float* Ho   = (float*)alloc((size_t)N * 40 * 4);
  float* s1   = (float*)alloc((size_t)N * 8 * 4);
  float* s2   = (float*)alloc((size_t)N * 8 * 4);
  float* s1o  = (float*)alloc((size_t)N * 4);
  float* s2o  = (float*)alloc((size_t)N * 4);
  int* deg    = (int*)alloc((size_t)N * 4);
  int* rp     = (int*)alloc((size_t)(N + 1) * 4);
  int* bsum   = (int*)alloc(256 * 4);
  int* scol   = (int*)alloc((size_t)E * 4);
  int* srow   = (int*)alloc((size_t)E * 4);
  float* w    = (float*)alloc((size_t)E * 8 * 4);
  float* wo   = (float*)alloc((size_t)E * 4);
  ushort* BpH = (ushort*)alloc((size_t)65536 * 2);
  ushort* BpL = (ushort*)alloc((size_t)65536 * 2);
  ushort* WgH = (ushort*)alloc((size_t)65536 * 2);
  ushort* WgL = (ushort*)alloc((size_t)65536 * 2);
  ushort* WeH = (ushort*)alloc((size_t)32768 * 2);
  ushort* WeL = (ushort*)alloc((size_t)32768 * 2);
  ushort* WoH = (ushort*)alloc((size_t)16384 * 2);
  ushort* WoL = (ushort*)alloc((size_t)16384 * 2);

  float* out0 = (float*)d_out;
  float* outY = out0 + (size_t)N * 40;
  float* outZ = outY + (size_t)N * 128;

  const int nb = (N + 255) / 256;
  const int gblk = (N + 63) / 64;

  // weight packing
  pack_watt_frag<<<dim3(256), dim3(256), 0, stream>>>(W_att, BpH, BpL);
  pack_b<256, 256><<<dim3(256), dim3(256), 0, stream>>>(W_gc, WgH, WgL);
  pack_b<128, 128><<<dim3(128), dim3(256), 0, stream>>>(W_enc, WeH, WeL);
  pack_b<40, 64><<<dim3(64), dim3(256), 0, stream>>>(W_out, WoH, WoL);

  // CSR build (counting sort by row)
  hipMemsetAsync(deg, 0, (size_t)N * 4, stream);
  hist_deg<<<dim3((E + 255) / 256), dim3(256), 0, stream>>>(row, deg, E);
  scan1<<<dim3(nb), dim3(256), 0, stream>>>(deg, rp, bsum, N);
  scan2<<<dim3(1), dim3(256), 0, stream>>>(bsum, nb);
  scan3<<<dim3(nb), dim3(256), 0, stream>>>(rp, bsum, N, E);
  hipMemsetAsync(deg, 0, (size_t)N * 4, stream);  // reuse as cursor
  scatter_edges<<<dim3((E + 255) / 256), dim3(256), 0, stream>>>(row, col, rp, deg, scol, srow, E);

  // layer 1: H = x @ W_att(all heads); f32 for s12, bf16 copy for gather
  gemm_mfma<256, 256, 1, false><<<dim3(gblk), dim3(256), 0, stream>>>(x, BpH, BpL, nullptr, bufA, hbuf, N);
  calc_s12<<<dim3((N * 8 + 255) / 256), dim3(256), 0, stream>>>(bufA, a1, a2, s1, s2, N);
  edge_w<<<dim3((E * 8 + 255) / 256), dim3(256), 0, stream>>>(srow, scol, s1, s2, w, E);
  agg_att<<<dim3(N), dim3(64), 0, stream>>>(hbuf, w, rp, scol, h1, N);

  // GraphConv: support in bf16 only
  gemm_mfma<256, 256, 2, false><<<dim3(gblk), dim3(256), 0, stream>>>(h1, WgH, WgL, nullptr, bufA, hbuf, N);
  agg_gc<<<dim3(N), dim3(64), 0, stream>>>(hbuf, rp, scol, b_gc, h2, N);

  // output head
  gemm_mfma<64, 40, 0, false><<<dim3(gblk), dim3(256), 0, stream>>>(h2, WoH, WoL, nullptr, Ho, nullptr, N);
  calc_s12_out<<<dim3((N + 255) / 256), dim3(256), 0, stream>>>(Ho, a1_out, a2_out, s1o, s2o, N);
  edge_wo<<<dim3((E + 255) / 256), dim3(256), 0, stream>>>(srow, scol, s1o, s2o, wo, E);
  agg_out_lsm<<<dim3(N), dim3(64), 0, stream>>>(Ho, wo, rp, scol, out0, N);

  // y, z
  gemm_mfma<128, 128, 0, true><<<dim3(gblk), dim3(256), 0, stream>>>(h1, WeH, WeL, b_enc, outY, nullptr, N);
  gemm_mfma<128, 128, 0, true><<<dim3(gblk), dim3(256), 0, stream>>>(h2, WeH, WeL, b_enc, outZ, nullptr, N);
}

// Round 9
// 504.317 us; speedup vs baseline: 2.0713x; 1.0135x over previous
//
#include <hip/hip_runtime.h>
#include <math.h>

// N=50000, E=800000, nfeat=256, hid=256, nclass=40, nstruc=128, heads=8
typedef __attribute__((ext_vector_type(8))) short short8;
typedef __attribute__((ext_vector_type(4))) ushort u16x4;
typedef __attribute__((ext_vector_type(8))) ushort u16x8;
typedef __attribute__((ext_vector_type(8))) __bf16 bf16x8;
typedef __attribute__((ext_vector_type(4))) float f32x4;

__device__ inline ushort f2bf(float x) {
  union { float f; unsigned u; } v; v.f = x;
  unsigned r = v.u + 0x7fff + ((v.u >> 16) & 1);
  return (ushort)(r >> 16);
}
__device__ inline float bf2f(ushort b) {
  union { unsigned u; float f; } v; v.u = (unsigned)b << 16; return v.f;
}

// ---------------- pack weights into MFMA fragment order (hi/lo split bf16) ----------------
// frag order: off = ((kb*(Fp/16)+nb)*64 + lane)*8 + j ; lane=(kr>>3)*16|(n&15), j=kr&7
template <int F, int Fp>
__global__ void pack_b(const float* __restrict__ B, ushort* __restrict__ hi,
                       ushort* __restrict__ lo) {
  int tid = blockIdx.x * blockDim.x + threadIdx.x;
  if (tid >= 256 * Fp) return;
  int k = tid / Fp, n = tid % Fp;
  float val = (n < F) ? B[k * F + n] : 0.f;
  ushort h = f2bf(val);
  ushort l = f2bf(val - bf2f(h));
  int kb = k >> 5, kr = k & 31;
  int lane = ((kr >> 3) << 4) | (n & 15);
  int j = kr & 7;
  int nb = n >> 4;
  size_t off = ((size_t)(kb * (Fp / 16) + nb) * 64 + lane) * 8 + j;
  hi[off] = h; lo[off] = l;
}

// W_att [8][256][32] -> logical B[k][n], n = h*32+j2
__global__ void pack_watt_frag(const float* __restrict__ W_att, ushort* __restrict__ hi,
                               ushort* __restrict__ lo) {
  int tid = blockIdx.x * blockDim.x + threadIdx.x;
  if (tid >= 256 * 256) return;
  int k = tid >> 8, n = tid & 255;
  float val = W_att[(size_t)(n >> 5) * 8192 + k * 32 + (n & 31)];
  ushort h = f2bf(val);
  ushort l = f2bf(val - bf2f(h));
  int kb = k >> 5, kr = k & 31;
  int lane = ((kr >> 3) << 4) | (n & 15);
  int j = kr & 7;
  int nb = n >> 4;
  size_t off = ((size_t)(kb * 16 + nb) * 64 + lane) * 8 + j;
  hi[off] = h; lo[off] = l;
}

// ---------------- split-bf16 MFMA GEMM: C[N,F] = A[N,256] @ B[256,F] (+bias) ----------------
// BM=32, 512 threads (8 waves: 2 row-groups x 4 col-groups), 32 KiB LDS -> 4 blocks/CU.
// OUTMODE: 0 = f32 only, 1 = f32 + bf16 copy, 2 = bf16 only
// BFIN: input already split hi/lo bf16 (Ahi/Alo) instead of f32 A.
template <int Fp, int F, int OUTMODE, bool BIAS, bool BFIN>
__global__ __launch_bounds__(512) void gemm_mfma(const float* __restrict__ A,
                                                 const ushort* __restrict__ Ahi,
                                                 const ushort* __restrict__ Alo,
                                                 const ushort* __restrict__ Bhi,
                                                 const ushort* __restrict__ Blo,
                                                 const float* __restrict__ bias,
                                                 float* __restrict__ C,
                                                 ushort* __restrict__ Cb, int N) {
  constexpr int NB = Fp / 64;  // 16-col fragments per wave (col-group covers Fp/4)
  __shared__ ushort lhs_hi[32 * 256];
  __shared__ ushort lhs_lo[32 * 256];
  int n0 = blockIdx.x * 32;
  int t = threadIdx.x;
  // ---- stage A tile (32x256, XOR-swizzled 16B units) ----
  {
    int r = t >> 4, q = t & 15;
    int row = n0 + r;
    bool rin = row < N;
#pragma unroll
    for (int i = 0; i < 2; ++i) {
      int c0 = q * 16 + i * 8;
      int c8 = (c0 >> 3) ^ (r & 7);
      if (BFIN) {
        u16x8 hv = (u16x8){0, 0, 0, 0, 0, 0, 0, 0};
        u16x8 lv = (u16x8){0, 0, 0, 0, 0, 0, 0, 0};
        if (rin) {
          hv = *reinterpret_cast<const u16x8*>(Ahi + (size_t)row * 256 + c0);
          lv = *reinterpret_cast<const u16x8*>(Alo + (size_t)row * 256 + c0);
        }
        *reinterpret_cast<u16x8*>(&lhs_hi[r * 256 + c8 * 8]) = hv;
        *reinterpret_cast<u16x8*>(&lhs_lo[r * 256 + c8 * 8]) = lv;
      } else {
        float4 f0 = {0.f, 0.f, 0.f, 0.f}, f1 = {0.f, 0.f, 0.f, 0.f};
        if (rin) {
          f0 = *reinterpret_cast<const float4*>(A + (size_t)row * 256 + c0);
          f1 = *reinterpret_cast<const float4*>(A + (size_t)row * 256 + c0 + 4);
        }
        float ff[8] = {f0.x, f0.y, f0.z, f0.w, f1.x, f1.y, f1.z, f1.w};
        short8 sh, sl;
#pragma unroll
        for (int j = 0; j < 8; ++j) {
          ushort hh = f2bf(ff[j]);
          sh[j] = (short)hh;
          sl[j] = (short)f2bf(ff[j] - bf2f(hh));
        }
        *reinterpret_cast<short8*>(&lhs_hi[r * 256 + c8 * 8]) = sh;
        *reinterpret_cast<short8*>(&lhs_lo[r * 256 + c8 * 8]) = sl;
      }
    }
  }
  __syncthreads();
  // ---- compute ----
  int w = t >> 6, l = t & 63;
  int wr = w >> 2, wc = w & 3;
  int lr = l & 15, lk = l >> 4;
  f32x4 acc[NB];
#pragma unroll
  for (int nb = 0; nb < NB; ++nb) acc[nb] = (f32x4){0.f, 0.f, 0.f, 0.f};

#pragma unroll
  for (int ks = 0; ks < 8; ++ks) {
    int row = wr * 16 + lr;
    int c8 = (ks * 4 + lk) ^ (row & 7);
    bf16x8 ah = *reinterpret_cast<const bf16x8*>(&lhs_hi[row * 256 + c8 * 8]);
    bf16x8 al = *reinterpret_cast<const bf16x8*>(&lhs_lo[row * 256 + c8 * 8]);
    bf16x8 bh[NB], bl[NB];
#pragma unroll
    for (int nb = 0; nb < NB; ++nb) {
      size_t off = ((size_t)(ks * (Fp / 16) + wc * NB + nb) * 64 + l) * 8;
      bh[nb] = *reinterpret_cast<const bf16x8*>(&Bhi[off]);
      bl[nb] = *reinterpret_cast<const bf16x8*>(&Blo[off]);
    }
#pragma unroll
    for (int nb = 0; nb < NB; ++nb) {
      acc[nb] = __builtin_amdgcn_mfma_f32_16x16x32_bf16(ah, bh[nb], acc[nb], 0, 0, 0);
      acc[nb] = __builtin_amdgcn_mfma_f32_16x16x32_bf16(ah, bl[nb], acc[nb], 0, 0, 0);
      acc[nb] = __builtin_amdgcn_mfma_f32_16x16x32_bf16(al, bh[nb], acc[nb], 0, 0, 0);
    }
  }
  // ---- write C: col=lane&15, row=(lane>>4)*4+reg ----
  int rowbase = n0 + wr * 16 + lk * 4;
#pragma unroll
  for (int nb = 0; nb < NB; ++nb) {
    int col = wc * (NB * 16) + nb * 16 + lr;
    if (col < F) {
      float bi = BIAS ? bias[col] : 0.f;
#pragma unroll
      for (int rg = 0; rg < 4; ++rg) {
        if (rowbase + rg < N) {
          float v = acc[nb][rg] + bi;
          if (OUTMODE != 2) C[(size_t)(rowbase + rg) * F + col] = v;
          if (OUTMODE != 0) Cb[(size_t)(rowbase + rg) * F + col] = f2bf(v);
        }
      }
    }
  }
}

// ---------------- s1/s2 per node per head ----------------
__global__ void calc_s12(const float* __restrict__ H, const float* __restrict__ a1,
                         const float* __restrict__ a2, float* __restrict__ s1,
                         float* __restrict__ s2, int N) {
  int tid = blockIdx.x * blockDim.x + threadIdx.x;
  if (tid >= N * 8) return;
  int h = tid & 7;
  int n = tid >> 3;
  const float* hp = H + (size_t)n * 256 + h * 32;
  const float* A1 = a1 + h * 32;
  const float* A2 = a2 + h * 32;
  float d1 = 0.f, d2 = 0.f;
#pragma unroll
  for (int j = 0; j < 32; ++j) {
    float v = hp[j];
    d1 = fmaf(v, A1[j], d1);
    d2 = fmaf(v, A2[j], d2);
  }
  s1[tid] = d1;
  s2[tid] = d2;
}

__global__ void calc_s12_out(const float* __restrict__ Ho, const float* __restrict__ a1o,
                             const float* __restrict__ a2o, float* __restrict__ s1o,
                             float* __restrict__ s2o, int N) {
  int n = blockIdx.x * blockDim.x + threadIdx.x;
  if (n >= N) return;
  const float* hp = Ho + (size_t)n * 40;
  float d1 = 0.f, d2 = 0.f;
#pragma unroll
  for (int j = 0; j < 40; ++j) {
    float v = hp[j];
    d1 = fmaf(v, a1o[j], d1);
    d2 = fmaf(v, a2o[j], d2);
  }
  s1o[n] = d1;
  s2o[n] = d2;
}

// ---------------- CSR build ----------------
__global__ void hist_deg(const int* __restrict__ row, int* __restrict__ deg, int E) {
  int e = blockIdx.x * blockDim.x + threadIdx.x;
  if (e < E) atomicAdd(&deg[row[e]], 1);
}

__global__ void scan1(const int* __restrict__ deg, int* __restrict__ rp, int* __restrict__ bsum,
                      int N) {
  __shared__ int sd[256];
  int t = threadIdx.x;
  int i = blockIdx.x * 256 + t;
  int v = (i < N) ? deg[i] : 0;
  sd[t] = v;
  __syncthreads();
  for (int off = 1; off < 256; off <<= 1) {
    int x = (t >= off) ? sd[t - off] : 0;
    __syncthreads();
    sd[t] += x;
    __syncthreads();
  }
  if (i < N) rp[i] = sd[t] - v;
  if (t == 255) bsum[blockIdx.x] = sd[255];
}

__global__ void scan2(int* __restrict__ bsum, int nb) {
  __shared__ int sd[256];
  int t = threadIdx.x;
  int v = (t < nb) ? bsum[t] : 0;
  sd[t] = v;
  __syncthreads();
  for (int off = 1; off < 256; off <<= 1) {
    int x = (t >= off) ? sd[t - off] : 0;
    __syncthreads();
    sd[t] += x;
    __syncthreads();
  }
  if (t < nb) bsum[t] = sd[t] - v;
}

__global__ void scan3(int* __restrict__ rp, const int* __restrict__ bsum, int N, int E) {
  int i = blockIdx.x * 256 + threadIdx.x;
  if (i < N) rp[i] += bsum[blockIdx.x];
  if (i == 0) rp[N] = E;
}

__global__ void scatter_edges(const int* __restrict__ row, const int* __restrict__ col,
                              const int* __restrict__ rp, int* __restrict__ cur,
                              int* __restrict__ scol, int* __restrict__ srow, int E) {
  int e = blockIdx.x * blockDim.x + threadIdx.x;
  if (e >= E) return;
  int r = row[e];
  int p = atomicAdd(&cur[r], 1);
  int idx = rp[r] + p;
  scol[idx] = col[e];
  srow[idx] = r;
}

// ---------------- edge weights ----------------
__global__ void edge_w(const int* __restrict__ srow, const int* __restrict__ scol,
                       const float* __restrict__ s1, const float* __restrict__ s2,
                       float* __restrict__ w, int E) {
  int tid = blockIdx.x * blockDim.x + threadIdx.x;
  if (tid >= E * 8) return;
  int e = tid >> 3, h = tid & 7;
  int r = srow[e], c = scol[e];
  float lg = s1[r * 8 + h] + s2[c * 8 + h];
  float lr = lg > 0.f ? lg : 0.2f * lg;
  w[tid] = expf(-lr);
}

__global__ void edge_wo(const int* __restrict__ srow, const int* __restrict__ scol,
                        const float* __restrict__ s1o, const float* __restrict__ s2o,
                        float* __restrict__ wo, int E) {
  int e = blockIdx.x * blockDim.x + threadIdx.x;
  if (e >= E) return;
  float lg = s1o[srow[e]] + s2o[scol[e]];
  float lr = lg > 0.f ? lg : 0.2f * lg;
  wo[e] = expf(-lr);
}

// ---------------- GAT layer-1 aggregation: one wave/node, 4 bf16/lane; emits h1 hi/lo ----------------
__global__ __launch_bounds__(64) void agg_att(const ushort* __restrict__ Hb,
                                              const float* __restrict__ w,
                                              const int* __restrict__ rp,
                                              const int* __restrict__ scol,
                                              ushort* __restrict__ h1hi,
                                              ushort* __restrict__ h1lo, int N) {
  int n = blockIdx.x;
  int t = threadIdx.x;          // features t*4..t*4+3 ; head = t>>3
  int head = t >> 3;
  float acc[4] = {0.f, 0.f, 0.f, 0.f};
  float rs = 0.f;
  int beg = rp[n], end = rp[n + 1];
  for (int i = beg; i < end; ++i) {
    int c = scol[i];
    float wv = w[i * 8 + head];
    rs += wv;
    const u16x4 hv = *reinterpret_cast<const u16x4*>(Hb + (size_t)c * 256 + t * 4);
#pragma unroll
    for (int j = 0; j < 4; ++j) acc[j] = fmaf(wv, bf2f(hv[j]), acc[j]);
  }
  float inv = 1.f / (rs + 1e-16f);
  u16x4 oh, ol;
#pragma unroll
  for (int j = 0; j < 4; ++j) {
    float v = acc[j] * inv;
    v = v > 0.f ? v : expm1f(v);
    ushort h = f2bf(v);
    oh[j] = h;
    ol[j] = f2bf(v - bf2f(h));
  }
  *reinterpret_cast<u16x4*>(h1hi + (size_t)n * 256 + t * 4) = oh;
  *reinterpret_cast<u16x4*>(h1lo + (size_t)n * 256 + t * 4) = ol;
}

// ---------------- GraphConv aggregation: one wave/node, 4 bf16/lane; emits h2 hi/lo ----------------
__global__ __launch_bounds__(64) void agg_gc(const ushort* __restrict__ Sb,
                                             const int* __restrict__ rp,
                                             const int* __restrict__ scol,
                                             const float* __restrict__ b_gc,
                                             ushort* __restrict__ h2hi,
                                             ushort* __restrict__ h2lo, int N) {
  int n = blockIdx.x;
  int t = threadIdx.x;
  float acc[4] = {0.f, 0.f, 0.f, 0.f};
  int beg = rp[n], end = rp[n + 1];
  for (int i = beg; i < end; ++i) {
    int c = scol[i];
    const u16x4 sv = *reinterpret_cast<const u16x4*>(Sb + (size_t)c * 256 + t * 4);
#pragma unroll
    for (int j = 0; j < 4; ++j) acc[j] += bf2f(sv[j]);
  }
  const float4 bv = *reinterpret_cast<const float4*>(b_gc + t * 4);
  float o[4] = {acc[0] + bv.x, acc[1] + bv.y, acc[2] + bv.z, acc[3] + bv.w};
  u16x4 oh, ol;
#pragma unroll
  for (int j = 0; j < 4; ++j) {
    ushort h = f2bf(o[j]);
    oh[j] = h;
    ol[j] = f2bf(o[j] - bf2f(h));
  }
  *reinterpret_cast<u16x4*>(h2hi + (size_t)n * 256 + t * 4) = oh;
  *reinterpret_cast<u16x4*>(h2lo + (size_t)n * 256 + t * 4) = ol;
}

// ---------------- output head aggregation + elu + log_softmax ----------------
__global__ __launch_bounds__(64) void agg_out_lsm(const float* __restrict__ Ho,
                                                  const float* __restrict__ wo,
                                                  const int* __restrict__ rp,
                                                  const int* __restrict__ scol,
                                                  float* __restrict__ out0, int N) {
  int n = blockIdx.x;
  int t = threadIdx.x;
  float acc = 0.f, rs = 0.f;
  int beg = rp[n], end = rp[n + 1];
  for (int i = beg; i < end; ++i) {
    int c = scol[i];
    float wv = wo[i];
    rs += wv;
    if (t < 40) acc = fmaf(wv, Ho[(size_t)c * 40 + t], acc);
  }
  float hp = acc / (rs + 1e-16f);
  float xo = (t < 40) ? (hp > 0.f ? hp : expm1f(hp)) : -3.0e38f;
  float mx = xo;
#pragma unroll
  for (int m = 1; m < 64; m <<= 1) mx = fmaxf(mx, __shfl_xor(mx, m));
  float ex = (t < 40) ? expf(xo - mx) : 0.f;
  float sum = ex;
#pragma unroll
  for (int m = 1; m < 64; m <<= 1) sum += __shfl_xor(sum, m);
  if (t < 40) out0[(size_t)n * 40 + t] = xo - mx - logf(sum);
}

// ---------------- launch ----------------
extern "C" void kernel_launch(void* const* d_in, const int* in_sizes, int n_in,
                              void* d_out, int out_size, void* d_ws, size_t ws_size,
                              hipStream_t stream) {
  const float* x      = (const float*)d_in[0];
  const int*   ei     = (const int*)d_in[1];
  const float* W_att  = (const float*)d_in[2];
  const float* a1     = (const float*)d_in[3];
  const float* a2     = (const float*)d_in[4];
  const float* W_out  = (const float*)d_in[5];
  const float* a1_out = (const float*)d_in[6];
  const float* a2_out = (const float*)d_in[7];
  const float* W_gc   = (const float*)d_in[8];
  const float* b_gc   = (const float*)d_in[9];
  const float* W_enc  = (const float*)d_in[10];
  const float* b_enc  = (const float*)d_in[11];

  const int N = in_sizes[0] / 256;
  const int E = in_sizes[1] / 2;
  const int* row = ei;
  const int* col = ei + E;

  char* p = (char*)d_ws;
  auto alloc = [&](size_t bytes) -> void* {
    void* r = (void*)p;
    p += (bytes + 255) & ~(size_t)255;
    return r;
  };
  float* bufA  = (float*)alloc((size_t)N * 256 * 4);   // H f32 (layer1, for s12)
  ushort* hbuf = (ushort*)alloc((size_t)N * 256 * 2);  // bf16 gather buf (H, then support)
  ushort* h1hi = (ushort*)alloc((size_t)N * 256 * 2);
  ushort* h1lo = (ushort*)alloc((size_t)N * 256 * 2);
  ushort* h2hi = (ushort*)alloc((size_t)N * 256 * 2);
  ushort* h2lo = (ushort*)alloc((size_t)N * 256 * 2);
  float* Ho   = (float*)alloc((size_t)N * 40 * 4);
  float* s1   = (float*)alloc((size_t)N * 8 * 4);
  float* s2   = (float*)alloc((size_t)N * 8 * 4);
  float* s1o  = (float*)alloc((size_t)N * 4);
  float* s2o  = (float*)alloc((size_t)N * 4);
  int* deg    = (int*)alloc((size_t)N * 4);
  int* rp     = (int*)alloc((size_t)(N + 1) * 4);
  int* bsum   = (int*)alloc(256 * 4);
  int* scol   = (int*)alloc((size_t)E * 4);
  int* srow   = (int*)alloc((size_t)E * 4);
  float* w    = (float*)alloc((size_t)E * 8 * 4);
  float* wo   = (float*)alloc((size_t)E * 4);
  ushort* BpH = (ushort*)alloc((size_t)65536 * 2);
  ushort* BpL = (ushort*)alloc((size_t)65536 * 2);
  ushort* WgH = (ushort*)alloc((size_t)65536 * 2);
  ushort* WgL = (ushort*)alloc((size_t)65536 * 2);
  ushort* WeH = (ushort*)alloc((size_t)32768 * 2);
  ushort* WeL = (ushort*)alloc((size_t)32768 * 2);
  ushort* WoH = (ushort*)alloc((size_t)16384 * 2);
  ushort* WoL = (ushort*)alloc((size_t)16384 * 2);

  float* out0 = (float*)d_out;
  float* outY = out0 + (size_t)N * 40;
  float* outZ = outY + (size_t)N * 128;

  const int nb = (N + 255) / 256;
  const int gblk = (N + 31) / 32;

  // weight packing
  pack_watt_frag<<<dim3(256), dim3(256), 0, stream>>>(W_att, BpH, BpL);
  pack_b<256, 256><<<dim3(256), dim3(256), 0, stream>>>(W_gc, WgH, WgL);
  pack_b<128, 128><<<dim3(128), dim3(256), 0, stream>>>(W_enc, WeH, WeL);
  pack_b<40, 64><<<dim3(64), dim3(256), 0, stream>>>(W_out, WoH, WoL);

  // CSR build (counting sort by row)
  hipMemsetAsync(deg, 0, (size_t)N * 4, stream);
  hist_deg<<<dim3((E + 255) / 256), dim3(256), 0, stream>>>(row, deg, E);
  scan1<<<dim3(nb), dim3(256), 0, stream>>>(deg, rp, bsum, N);
  scan2<<<dim3(1), dim3(256), 0, stream>>>(bsum, nb);
  scan3<<<dim3(nb), dim3(256), 0, stream>>>(rp, bsum, N, E);
  hipMemsetAsync(deg, 0, (size_t)N * 4, stream);  // reuse as cursor
  scatter_edges<<<dim3((E + 255) / 256), dim3(256), 0, stream>>>(row, col, rp, deg, scol, srow, E);

  // layer 1: H = x @ W_att(all heads); f32 for s12, bf16 copy for gather
  gemm_mfma<256, 256, 1, false, false><<<dim3(gblk), dim3(512), 0, stream>>>(
      x, nullptr, nullptr, BpH, BpL, nullptr, bufA, hbuf, N);
  calc_s12<<<dim3((N * 8 + 255) / 256), dim3(256), 0, stream>>>(bufA, a1, a2, s1, s2, N);
  edge_w<<<dim3((E * 8 + 255) / 256), dim3(256), 0, stream>>>(srow, scol, s1, s2, w, E);
  agg_att<<<dim3(N), dim3(64), 0, stream>>>(hbuf, w, rp, scol, h1hi, h1lo, N);

  // GraphConv: support in bf16 only
  gemm_mfma<256, 256, 2, false, true><<<dim3(gblk), dim3(512), 0, stream>>>(
      nullptr, h1hi, h1lo, WgH, WgL, nullptr, nullptr, hbuf, N);
  agg_gc<<<dim3(N), dim3(64), 0, stream>>>(hbuf, rp, scol, b_gc, h2hi, h2lo, N);

  // output head
  gemm_mfma<64, 40, 0, false, true><<<dim3(gblk), dim3(512), 0, stream>>>(
      nullptr, h2hi, h2lo, WoH, WoL, nullptr, Ho, nullptr, N);
  calc_s12_out<<<dim3((N + 255) / 256), dim3(256), 0, stream>>>(Ho, a1_out, a2_out, s1o, s2o, N);
  edge_wo<<<dim3((E + 255) / 256), dim3(256), 0, stream>>>(srow, scol, s1o, s2o, wo, E);
  agg_out_lsm<<<dim3(N), dim3(64), 0, stream>>>(Ho, wo, rp, scol, out0, N);

  // y, z
  gemm_mfma<128, 128, 0, true, true><<<dim3(gblk), dim3(512), 0, stream>>>(
      nullptr, h1hi, h1lo, WeH, WeL, b_enc, outY, nullptr, N);
  gemm_mfma<128, 128, 0, true, true><<<dim3(gblk), dim3(512), 0, stream>>>(
      nullptr, h2hi, h2lo, WeH, WeL, b_enc, outZ, nullptr, N);
}

// Round 10
// 466.514 us; speedup vs baseline: 2.2391x; 1.0810x over previous
//
#include <hip/hip_runtime.h>
#include <math.h>

// N=50000, E=800000, nfeat=256, hid=256, nclass=40, nstruc=128, heads=8
typedef __attribute__((ext_vector_type(8))) short short8;
typedef __attribute__((ext_vector_type(4))) ushort u16x4;
typedef __attribute__((ext_vector_type(8))) ushort u16x8;
typedef __attribute__((ext_vector_type(8))) __bf16 bf16x8;
typedef __attribute__((ext_vector_type(4))) float f32x4;

__device__ inline ushort f2bf(float x) {
  union { float f; unsigned u; } v; v.f = x;
  unsigned r = v.u + 0x7fff + ((v.u >> 16) & 1);
  return (ushort)(r >> 16);
}
__device__ inline float bf2f(ushort b) {
  union { unsigned u; float f; } v; v.u = (unsigned)b << 16; return v.f;
}

// ---------------- pack weights into MFMA fragment order (hi/lo split bf16) ----------------
// frag order: off = ((kb*(Fp/16)+nb)*64 + lane)*8 + j ; lane=(kr>>3)*16|(n&15), j=kr&7
template <int F, int Fp>
__global__ void pack_b(const float* __restrict__ B, ushort* __restrict__ hi,
                       ushort* __restrict__ lo) {
  int tid = blockIdx.x * blockDim.x + threadIdx.x;
  if (tid >= 256 * Fp) return;
  int k = tid / Fp, n = tid % Fp;
  float val = (n < F) ? B[k * F + n] : 0.f;
  ushort h = f2bf(val);
  ushort l = f2bf(val - bf2f(h));
  int kb = k >> 5, kr = k & 31;
  int lane = ((kr >> 3) << 4) | (n & 15);
  int j = kr & 7;
  int nb = n >> 4;
  size_t off = ((size_t)(kb * (Fp / 16) + nb) * 64 + lane) * 8 + j;
  hi[off] = h; lo[off] = l;
}

// W_att [8][256][32] -> logical B[k][n], n = h*32+j2
__global__ void pack_watt_frag(const float* __restrict__ W_att, ushort* __restrict__ hi,
                               ushort* __restrict__ lo) {
  int tid = blockIdx.x * blockDim.x + threadIdx.x;
  if (tid >= 256 * 256) return;
  int k = tid >> 8, n = tid & 255;
  float val = W_att[(size_t)(n >> 5) * 8192 + k * 32 + (n & 31)];
  ushort h = f2bf(val);
  ushort l = f2bf(val - bf2f(h));
  int kb = k >> 5, kr = k & 31;
  int lane = ((kr >> 3) << 4) | (n & 15);
  int j = kr & 7;
  int nb = n >> 4;
  size_t off = ((size_t)(kb * 16 + nb) * 64 + lane) * 8 + j;
  hi[off] = h; lo[off] = l;
}

// ---------------- bf16-A MFMA GEMM: C[N,F] = A[N,256] @ B[256,F] (+bias) ----------------
// BM=32, 512 threads (8 waves: 2 row-groups x 4 col-groups), 16 KiB LDS.
// A single bf16 (rounded); B hi/lo split -> 2 MFMA per fragment pair.
// OUTMODE: 0 = f32 only, 1 = f32 + bf16 copy, 2 = bf16 only
// BFIN: input already bf16 (Ab) instead of f32 A.
template <int Fp, int F, int OUTMODE, bool BIAS, bool BFIN>
__global__ __launch_bounds__(512) void gemm_mfma(const float* __restrict__ A,
                                                 const ushort* __restrict__ Ab,
                                                 const ushort* __restrict__ Bhi,
                                                 const ushort* __restrict__ Blo,
                                                 const float* __restrict__ bias,
                                                 float* __restrict__ C,
                                                 ushort* __restrict__ Cb, int N) {
  constexpr int NB = Fp / 64;  // 16-col fragments per wave (col-group covers Fp/4)
  __shared__ ushort lhs[32 * 256];
  int n0 = blockIdx.x * 32;
  int t = threadIdx.x;
  // ---- stage A tile (32x256 bf16, XOR-swizzled 16B units) ----
  {
    int r = t >> 4, q = t & 15;
    int row = n0 + r;
    bool rin = row < N;
#pragma unroll
    for (int i = 0; i < 2; ++i) {
      int c0 = q * 16 + i * 8;
      int c8 = (c0 >> 3) ^ (r & 7);
      if (BFIN) {
        u16x8 hv = (u16x8){0, 0, 0, 0, 0, 0, 0, 0};
        if (rin) hv = *reinterpret_cast<const u16x8*>(Ab + (size_t)row * 256 + c0);
        *reinterpret_cast<u16x8*>(&lhs[r * 256 + c8 * 8]) = hv;
      } else {
        float4 f0 = {0.f, 0.f, 0.f, 0.f}, f1 = {0.f, 0.f, 0.f, 0.f};
        if (rin) {
          f0 = *reinterpret_cast<const float4*>(A + (size_t)row * 256 + c0);
          f1 = *reinterpret_cast<const float4*>(A + (size_t)row * 256 + c0 + 4);
        }
        float ff[8] = {f0.x, f0.y, f0.z, f0.w, f1.x, f1.y, f1.z, f1.w};
        short8 sh;
#pragma unroll
        for (int j = 0; j < 8; ++j) sh[j] = (short)f2bf(ff[j]);
        *reinterpret_cast<short8*>(&lhs[r * 256 + c8 * 8]) = sh;
      }
    }
  }
  __syncthreads();
  // ---- compute ----
  int w = t >> 6, l = t & 63;
  int wr = w >> 2, wc = w & 3;
  int lr = l & 15, lk = l >> 4;
  f32x4 acc[NB];
#pragma unroll
  for (int nb = 0; nb < NB; ++nb) acc[nb] = (f32x4){0.f, 0.f, 0.f, 0.f};

#pragma unroll
  for (int ks = 0; ks < 8; ++ks) {
    int row = wr * 16 + lr;
    int c8 = (ks * 4 + lk) ^ (row & 7);
    bf16x8 ah = *reinterpret_cast<const bf16x8*>(&lhs[row * 256 + c8 * 8]);
#pragma unroll
    for (int nb = 0; nb < NB; ++nb) {
      size_t off = ((size_t)(ks * (Fp / 16) + wc * NB + nb) * 64 + l) * 8;
      bf16x8 bh = *reinterpret_cast<const bf16x8*>(&Bhi[off]);
      bf16x8 bl = *reinterpret_cast<const bf16x8*>(&Blo[off]);
      acc[nb] = __builtin_amdgcn_mfma_f32_16x16x32_bf16(ah, bh, acc[nb], 0, 0, 0);
      acc[nb] = __builtin_amdgcn_mfma_f32_16x16x32_bf16(ah, bl, acc[nb], 0, 0, 0);
    }
  }
  // ---- write C: col=lane&15, row=(lane>>4)*4+reg ----
  int rowbase = n0 + wr * 16 + lk * 4;
#pragma unroll
  for (int nb = 0; nb < NB; ++nb) {
    int col = wc * (NB * 16) + nb * 16 + lr;
    if (col < F) {
      float bi = BIAS ? bias[col] : 0.f;
#pragma unroll
      for (int rg = 0; rg < 4; ++rg) {
        if (rowbase + rg < N) {
          float v = acc[nb][rg] + bi;
          if (OUTMODE != 2) C[(size_t)(rowbase + rg) * F + col] = v;
          if (OUTMODE != 0) Cb[(size_t)(rowbase + rg) * F + col] = f2bf(v);
        }
      }
    }
  }
}

// ---------------- s1/s2 per node per head (bf16 H input) ----------------
__global__ void calc_s12(const ushort* __restrict__ Hb, const float* __restrict__ a1,
                         const float* __restrict__ a2, float* __restrict__ s1,
                         float* __restrict__ s2, int N) {
  int tid = blockIdx.x * blockDim.x + threadIdx.x;
  if (tid >= N * 8) return;
  int h = tid & 7;
  int n = tid >> 3;
  const ushort* hp = Hb + (size_t)n * 256 + h * 32;
  const float* A1 = a1 + h * 32;
  const float* A2 = a2 + h * 32;
  float d1 = 0.f, d2 = 0.f;
#pragma unroll
  for (int j0 = 0; j0 < 32; j0 += 8) {
    u16x8 hv = *reinterpret_cast<const u16x8*>(hp + j0);
#pragma unroll
    for (int j = 0; j < 8; ++j) {
      float v = bf2f(hv[j]);
      d1 = fmaf(v, A1[j0 + j], d1);
      d2 = fmaf(v, A2[j0 + j], d2);
    }
  }
  s1[tid] = d1;
  s2[tid] = d2;
}

__global__ void calc_s12_out(const float* __restrict__ Ho, const float* __restrict__ a1o,
                             const float* __restrict__ a2o, float* __restrict__ s1o,
                             float* __restrict__ s2o, int N) {
  int n = blockIdx.x * blockDim.x + threadIdx.x;
  if (n >= N) return;
  const float* hp = Ho + (size_t)n * 40;
  float d1 = 0.f, d2 = 0.f;
#pragma unroll
  for (int j = 0; j < 40; ++j) {
    float v = hp[j];
    d1 = fmaf(v, a1o[j], d1);
    d2 = fmaf(v, a2o[j], d2);
  }
  s1o[n] = d1;
  s2o[n] = d2;
}

// ---------------- CSR build ----------------
__global__ void hist_deg(const int* __restrict__ row, int* __restrict__ deg, int E) {
  int e = blockIdx.x * blockDim.x + threadIdx.x;
  if (e < E) atomicAdd(&deg[row[e]], 1);
}

__global__ void scan1(const int* __restrict__ deg, int* __restrict__ rp, int* __restrict__ bsum,
                      int N) {
  __shared__ int sd[256];
  int t = threadIdx.x;
  int i = blockIdx.x * 256 + t;
  int v = (i < N) ? deg[i] : 0;
  sd[t] = v;
  __syncthreads();
  for (int off = 1; off < 256; off <<= 1) {
    int x = (t >= off) ? sd[t - off] : 0;
    __syncthreads();
    sd[t] += x;
    __syncthreads();
  }
  if (i < N) rp[i] = sd[t] - v;
  if (t == 255) bsum[blockIdx.x] = sd[255];
}

__global__ void scan2(int* __restrict__ bsum, int nb) {
  __shared__ int sd[256];
  int t = threadIdx.x;
  int v = (t < nb) ? bsum[t] : 0;
  sd[t] = v;
  __syncthreads();
  for (int off = 1; off < 256; off <<= 1) {
    int x = (t >= off) ? sd[t - off] : 0;
    __syncthreads();
    sd[t] += x;
    __syncthreads();
  }
  if (t < nb) bsum[t] = sd[t] - v;
}

__global__ void scan3(int* __restrict__ rp, const int* __restrict__ bsum, int N, int E) {
  int i = blockIdx.x * 256 + threadIdx.x;
  if (i < N) rp[i] += bsum[blockIdx.x];
  if (i == 0) rp[N] = E;
}

__global__ void scatter_edges(const int* __restrict__ row, const int* __restrict__ col,
                              const int* __restrict__ rp, int* __restrict__ cur,
                              int* __restrict__ scol, int E) {
  int e = blockIdx.x * blockDim.x + threadIdx.x;
  if (e >= E) return;
  int r = row[e];
  int p = atomicAdd(&cur[r], 1);
  scol[rp[r] + p] = col[e];
}

// ---------------- GAT layer-1 aggregation (fused edge weights): one wave/node ----------------
__global__ __launch_bounds__(64) void agg_att(const ushort* __restrict__ Hb,
                                              const float* __restrict__ s1,
                                              const float* __restrict__ s2,
                                              const int* __restrict__ rp,
                                              const int* __restrict__ scol,
                                              ushort* __restrict__ h1b, int N) {
  int n = blockIdx.x;
  int t = threadIdx.x;          // features t*4..t*4+3 ; head = t>>3
  int head = t >> 3;
  float s1n = s1[n * 8 + head];
  float acc[4] = {0.f, 0.f, 0.f, 0.f};
  float rs = 0.f;
  int beg = rp[n], end = rp[n + 1];
  for (int i = beg; i < end; ++i) {
    int c = scol[i];
    float lg = s1n + s2[c * 8 + head];
    float lr = lg > 0.f ? lg : 0.2f * lg;
    float wv = expf(-lr);
    rs += wv;
    const u16x4 hv = *reinterpret_cast<const u16x4*>(Hb + (size_t)c * 256 + t * 4);
#pragma unroll
    for (int j = 0; j < 4; ++j) acc[j] = fmaf(wv, bf2f(hv[j]), acc[j]);
  }
  float inv = 1.f / (rs + 1e-16f);
  u16x4 ov;
#pragma unroll
  for (int j = 0; j < 4; ++j) {
    float v = acc[j] * inv;
    v = v > 0.f ? v : expm1f(v);
    ov[j] = f2bf(v);
  }
  *reinterpret_cast<u16x4*>(h1b + (size_t)n * 256 + t * 4) = ov;
}

// ---------------- GraphConv aggregation: one wave/node ----------------
__global__ __launch_bounds__(64) void agg_gc(const ushort* __restrict__ Sb,
                                             const int* __restrict__ rp,
                                             const int* __restrict__ scol,
                                             const float* __restrict__ b_gc,
                                             ushort* __restrict__ h2b, int N) {
  int n = blockIdx.x;
  int t = threadIdx.x;
  float acc[4] = {0.f, 0.f, 0.f, 0.f};
  int beg = rp[n], end = rp[n + 1];
  for (int i = beg; i < end; ++i) {
    int c = scol[i];
    const u16x4 sv = *reinterpret_cast<const u16x4*>(Sb + (size_t)c * 256 + t * 4);
#pragma unroll
    for (int j = 0; j < 4; ++j) acc[j] += bf2f(sv[j]);
  }
  const float4 bv = *reinterpret_cast<const float4*>(b_gc + t * 4);
  float o[4] = {acc[0] + bv.x, acc[1] + bv.y, acc[2] + bv.z, acc[3] + bv.w};
  u16x4 ov;
#pragma unroll
  for (int j = 0; j < 4; ++j) ov[j] = f2bf(o[j]);
  *reinterpret_cast<u16x4*>(h2b + (size_t)n * 256 + t * 4) = ov;
}

// ---------------- output head aggregation (fused weights) + elu + log_softmax ----------------
__global__ __launch_bounds__(64) void agg_out_lsm(const float* __restrict__ Ho,
                                                  const float* __restrict__ s1o,
                                                  const float* __restrict__ s2o,
                                                  const int* __restrict__ rp,
                                                  const int* __restrict__ scol,
                                                  float* __restrict__ out0, int N) {
  int n = blockIdx.x;
  int t = threadIdx.x;
  float s1n = s1o[n];
  float acc = 0.f, rs = 0.f;
  int beg = rp[n], end = rp[n + 1];
  for (int i = beg; i < end; ++i) {
    int c = scol[i];
    float lg = s1n + s2o[c];
    float lr = lg > 0.f ? lg : 0.2f * lg;
    float wv = expf(-lr);
    rs += wv;
    if (t < 40) acc = fmaf(wv, Ho[(size_t)c * 40 + t], acc);
  }
  float hp = acc / (rs + 1e-16f);
  float xo = (t < 40) ? (hp > 0.f ? hp : expm1f(hp)) : -3.0e38f;
  float mx = xo;
#pragma unroll
  for (int m = 1; m < 64; m <<= 1) mx = fmaxf(mx, __shfl_xor(mx, m));
  float ex = (t < 40) ? expf(xo - mx) : 0.f;
  float sum = ex;
#pragma unroll
  for (int m = 1; m < 64; m <<= 1) sum += __shfl_xor(sum, m);
  if (t < 40) out0[(size_t)n * 40 + t] = xo - mx - logf(sum);
}

// ---------------- launch ----------------
extern "C" void kernel_launch(void* const* d_in, const int* in_sizes, int n_in,
                              void* d_out, int out_size, void* d_ws, size_t ws_size,
                              hipStream_t stream) {
  const float* x      = (const float*)d_in[0];
  const int*   ei     = (const int*)d_in[1];
  const float* W_att  = (const float*)d_in[2];
  const float* a1     = (const float*)d_in[3];
  const float* a2     = (const float*)d_in[4];
  const float* W_out  = (const float*)d_in[5];
  const float* a1_out = (const float*)d_in[6];
  const float* a2_out = (const float*)d_in[7];
  const float* W_gc   = (const float*)d_in[8];
  const float* b_gc   = (const float*)d_in[9];
  const float* W_enc  = (const float*)d_in[10];
  const float* b_enc  = (const float*)d_in[11];

  const int N = in_sizes[0] / 256;
  const int E = in_sizes[1] / 2;
  const int* row = ei;
  const int* col = ei + E;

  char* p = (char*)d_ws;
  auto alloc = [&](size_t bytes) -> void* {
    void* r = (void*)p;
    p += (bytes + 255) & ~(size_t)255;
    return r;
  };
  ushort* hbuf = (ushort*)alloc((size_t)N * 256 * 2);  // bf16: H, then support
  ushort* h1b  = (ushort*)alloc((size_t)N * 256 * 2);
  ushort* h2b  = (ushort*)alloc((size_t)N * 256 * 2);
  float* Ho   = (float*)alloc((size_t)N * 40 * 4);
  float* s1   = (float*)alloc((size_t)N * 8 * 4);
  float* s2   = (float*)alloc((size_t)N * 8 * 4);
  float* s1o  = (float*)alloc((size_t)N * 4);
  float* s2o  = (float*)alloc((size_t)N * 4);
  int* deg    = (int*)alloc((size_t)N * 4);
  int* rp     = (int*)alloc((size_t)(N + 1) * 4);
  int* bsum   = (int*)alloc(256 * 4);
  int* scol   = (int*)alloc((size_t)E * 4);
  ushort* BpH = (ushort*)alloc((size_t)65536 * 2);
  ushort* BpL = (ushort*)alloc((size_t)65536 * 2);
  ushort* WgH = (ushort*)alloc((size_t)65536 * 2);
  ushort* WgL = (ushort*)alloc((size_t)65536 * 2);
  ushort* WeH = (ushort*)alloc((size_t)32768 * 2);
  ushort* WeL = (ushort*)alloc((size_t)32768 * 2);
  ushort* WoH = (ushort*)alloc((size_t)16384 * 2);
  ushort* WoL = (ushort*)alloc((size_t)16384 * 2);

  float* out0 = (float*)d_out;
  float* outY = out0 + (size_t)N * 40;
  float* outZ = outY + (size_t)N * 128;

  const int nb = (N + 255) / 256;
  const int gblk = (N + 31) / 32;

  // weight packing
  pack_watt_frag<<<dim3(256), dim3(256), 0, stream>>>(W_att, BpH, BpL);
  pack_b<256, 256><<<dim3(256), dim3(256), 0, stream>>>(W_gc, WgH, WgL);
  pack_b<128, 128><<<dim3(128), dim3(256), 0, stream>>>(W_enc, WeH, WeL);
  pack_b<40, 64><<<dim3(64), dim3(256), 0, stream>>>(W_out, WoH, WoL);

  // CSR build (counting sort by row)
  hipMemsetAsync(deg, 0, (size_t)N * 4, stream);
  hist_deg<<<dim3((E + 255) / 256), dim3(256), 0, stream>>>(row, deg, E);
  scan1<<<dim3(nb), dim3(256), 0, stream>>>(deg, rp, bsum, N);
  scan2<<<dim3(1), dim3(256), 0, stream>>>(bsum, nb);
  scan3<<<dim3(nb), dim3(256), 0, stream>>>(rp, bsum, N, E);
  hipMemsetAsync(deg, 0, (size_t)N * 4, stream);  // reuse as cursor
  scatter_edges<<<dim3((E + 255) / 256), dim3(256), 0, stream>>>(row, col, rp, deg, scol, E);

  // layer 1: H = x @ W_att(all heads), bf16 out
  gemm_mfma<256, 256, 2, false, false><<<dim3(gblk), dim3(512), 0, stream>>>(
      x, nullptr, BpH, BpL, nullptr, nullptr, hbuf, N);
  calc_s12<<<dim3((N * 8 + 255) / 256), dim3(256), 0, stream>>>(hbuf, a1, a2, s1, s2, N);
  agg_att<<<dim3(N), dim3(64), 0, stream>>>(hbuf, s1, s2, rp, scol, h1b, N);

  // GraphConv: support bf16 (overwrites hbuf)
  gemm_mfma<256, 256, 2, false, true><<<dim3(gblk), dim3(512), 0, stream>>>(
      nullptr, h1b, WgH, WgL, nullptr, nullptr, hbuf, N);
  agg_gc<<<dim3(N), dim3(64), 0, stream>>>(hbuf, rp, scol, b_gc, h2b, N);

  // output head
  gemm_mfma<64, 40, 0, false, true><<<dim3(gblk), dim3(512), 0, stream>>>(
      nullptr, h2b, WoH, WoL, nullptr, Ho, nullptr, N);
  calc_s12_out<<<dim3((N + 255) / 256), dim3(256), 0, stream>>>(Ho, a1_out, a2_out, s1o, s2o, N);
  agg_out_lsm<<<dim3(N), dim3(64), 0, stream>>>(Ho, s1o, s2o, rp, scol, out0, N);

  // y, z
  gemm_mfma<128, 128, 0, true, true><<<dim3(gblk), dim3(512), 0, stream>>>(
      nullptr, h1b, WeH, WeL, b_enc, outY, nullptr, N);
  gemm_mfma<128, 128, 0, true, true><<<dim3(gblk), dim3(512), 0, stream>>>(
      nullptr, h2b, WeH, WeL, b_enc, outZ, nullptr, N);
}

// Round 11
// 459.047 us; speedup vs baseline: 2.2756x; 1.0163x over previous
//
#include <hip/hip_runtime.h>
#include <math.h>

// N=50000, E=800000, nfeat=256, hid=256, nclass=40, nstruc=128, heads=8
typedef __attribute__((ext_vector_type(8))) short short8;
typedef __attribute__((ext_vector_type(4))) ushort u16x4;
typedef __attribute__((ext_vector_type(8))) ushort u16x8;
typedef __attribute__((ext_vector_type(8))) __bf16 bf16x8;
typedef __attribute__((ext_vector_type(4))) float f32x4;

__device__ inline ushort f2bf(float x) {
  union { float f; unsigned u; } v; v.f = x;
  unsigned r = v.u + 0x7fff + ((v.u >> 16) & 1);
  return (ushort)(r >> 16);
}
__device__ inline float bf2f(ushort b) {
  union { unsigned u; float f; } v; v.u = (unsigned)b << 16; return v.f;
}

// ---------------- pack weights into MFMA fragment order (hi/lo split bf16) ----------------
template <int F, int Fp>
__global__ void pack_b(const float* __restrict__ B, ushort* __restrict__ hi,
                       ushort* __restrict__ lo) {
  int tid = blockIdx.x * blockDim.x + threadIdx.x;
  if (tid >= 256 * Fp) return;
  int k = tid / Fp, n = tid % Fp;
  float val = (n < F) ? B[k * F + n] : 0.f;
  ushort h = f2bf(val);
  ushort l = f2bf(val - bf2f(h));
  int kb = k >> 5, kr = k & 31;
  int lane = ((kr >> 3) << 4) | (n & 15);
  int j = kr & 7;
  int nb = n >> 4;
  size_t off = ((size_t)(kb * (Fp / 16) + nb) * 64 + lane) * 8 + j;
  hi[off] = h; lo[off] = l;
}

// W_att [8][256][32] -> logical B[k][n], n = h*32+j2
__global__ void pack_watt_frag(const float* __restrict__ W_att, ushort* __restrict__ hi,
                               ushort* __restrict__ lo) {
  int tid = blockIdx.x * blockDim.x + threadIdx.x;
  if (tid >= 256 * 256) return;
  int k = tid >> 8, n = tid & 255;
  float val = W_att[(size_t)(n >> 5) * 8192 + k * 32 + (n & 31)];
  ushort h = f2bf(val);
  ushort l = f2bf(val - bf2f(h));
  int kb = k >> 5, kr = k & 31;
  int lane = ((kr >> 3) << 4) | (n & 15);
  int j = kr & 7;
  int nb = n >> 4;
  size_t off = ((size_t)(kb * 16 + nb) * 64 + lane) * 8 + j;
  hi[off] = h; lo[off] = l;
}

// ---------------- bf16-A MFMA GEMM ----------------
// OUTMODE: 0 = f32 only, 1 = f32 + bf16 copy, 2 = bf16 only
template <int Fp, int F, int OUTMODE, bool BIAS, bool BFIN>
__global__ __launch_bounds__(512) void gemm_mfma(const float* __restrict__ A,
                                                 const ushort* __restrict__ Ab,
                                                 const ushort* __restrict__ Bhi,
                                                 const ushort* __restrict__ Blo,
                                                 const float* __restrict__ bias,
                                                 float* __restrict__ C,
                                                 ushort* __restrict__ Cb, int N) {
  constexpr int NB = Fp / 64;
  __shared__ ushort lhs[32 * 256];
  int n0 = blockIdx.x * 32;
  int t = threadIdx.x;
  {
    int r = t >> 4, q = t & 15;
    int row = n0 + r;
    bool rin = row < N;
#pragma unroll
    for (int i = 0; i < 2; ++i) {
      int c0 = q * 16 + i * 8;
      int c8 = (c0 >> 3) ^ (r & 7);
      if (BFIN) {
        u16x8 hv = (u16x8){0, 0, 0, 0, 0, 0, 0, 0};
        if (rin) hv = *reinterpret_cast<const u16x8*>(Ab + (size_t)row * 256 + c0);
        *reinterpret_cast<u16x8*>(&lhs[r * 256 + c8 * 8]) = hv;
      } else {
        float4 f0 = {0.f, 0.f, 0.f, 0.f}, f1 = {0.f, 0.f, 0.f, 0.f};
        if (rin) {
          f0 = *reinterpret_cast<const float4*>(A + (size_t)row * 256 + c0);
          f1 = *reinterpret_cast<const float4*>(A + (size_t)row * 256 + c0 + 4);
        }
        float ff[8] = {f0.x, f0.y, f0.z, f0.w, f1.x, f1.y, f1.z, f1.w};
        short8 sh;
#pragma unroll
        for (int j = 0; j < 8; ++j) sh[j] = (short)f2bf(ff[j]);
        *reinterpret_cast<short8*>(&lhs[r * 256 + c8 * 8]) = sh;
      }
    }
  }
  __syncthreads();
  int w = t >> 6, l = t & 63;
  int wr = w >> 2, wc = w & 3;
  int lr = l & 15, lk = l >> 4;
  f32x4 acc[NB];
#pragma unroll
  for (int nb = 0; nb < NB; ++nb) acc[nb] = (f32x4){0.f, 0.f, 0.f, 0.f};

#pragma unroll
  for (int ks = 0; ks < 8; ++ks) {
    int row = wr * 16 + lr;
    int c8 = (ks * 4 + lk) ^ (row & 7);
    bf16x8 ah = *reinterpret_cast<const bf16x8*>(&lhs[row * 256 + c8 * 8]);
#pragma unroll
    for (int nb = 0; nb < NB; ++nb) {
      size_t off = ((size_t)(ks * (Fp / 16) + wc * NB + nb) * 64 + l) * 8;
      bf16x8 bh = *reinterpret_cast<const bf16x8*>(&Bhi[off]);
      bf16x8 bl = *reinterpret_cast<const bf16x8*>(&Blo[off]);
      acc[nb] = __builtin_amdgcn_mfma_f32_16x16x32_bf16(ah, bh, acc[nb], 0, 0, 0);
      acc[nb] = __builtin_amdgcn_mfma_f32_16x16x32_bf16(ah, bl, acc[nb], 0, 0, 0);
    }
  }
  int rowbase = n0 + wr * 16 + lk * 4;
#pragma unroll
  for (int nb = 0; nb < NB; ++nb) {
    int col = wc * (NB * 16) + nb * 16 + lr;
    if (col < F) {
      float bi = BIAS ? bias[col] : 0.f;
#pragma unroll
      for (int rg = 0; rg < 4; ++rg) {
        if (rowbase + rg < N) {
          float v = acc[nb][rg] + bi;
          if (OUTMODE != 2) C[(size_t)(rowbase + rg) * F + col] = v;
          if (OUTMODE != 0) Cb[(size_t)(rowbase + rg) * F + col] = f2bf(v);
        }
      }
    }
  }
}

// ---------------- s1/s2 per node per head (bf16 H input) ----------------
__global__ void calc_s12(const ushort* __restrict__ Hb, const float* __restrict__ a1,
                         const float* __restrict__ a2, float* __restrict__ s1,
                         float* __restrict__ s2, int N) {
  int tid = blockIdx.x * blockDim.x + threadIdx.x;
  if (tid >= N * 8) return;
  int h = tid & 7;
  int n = tid >> 3;
  const ushort* hp = Hb + (size_t)n * 256 + h * 32;
  const float* A1 = a1 + h * 32;
  const float* A2 = a2 + h * 32;
  float d1 = 0.f, d2 = 0.f;
#pragma unroll
  for (int j0 = 0; j0 < 32; j0 += 8) {
    u16x8 hv = *reinterpret_cast<const u16x8*>(hp + j0);
#pragma unroll
    for (int j = 0; j < 8; ++j) {
      float v = bf2f(hv[j]);
      d1 = fmaf(v, A1[j0 + j], d1);
      d2 = fmaf(v, A2[j0 + j], d2);
    }
  }
  s1[tid] = d1;
  s2[tid] = d2;
}

__global__ void calc_s12_out(const float* __restrict__ Ho, const float* __restrict__ a1o,
                             const float* __restrict__ a2o, float* __restrict__ s1o,
                             float* __restrict__ s2o, int N) {
  int n = blockIdx.x * blockDim.x + threadIdx.x;
  if (n >= N) return;
  const float* hp = Ho + (size_t)n * 40;
  float d1 = 0.f, d2 = 0.f;
#pragma unroll
  for (int j = 0; j < 40; ++j) {
    float v = hp[j];
    d1 = fmaf(v, a1o[j], d1);
    d2 = fmaf(v, a2o[j], d2);
  }
  s1o[n] = d1;
  s2o[n] = d2;
}

// ---------------- CSR build ----------------
__global__ void hist_deg(const int* __restrict__ row, int* __restrict__ deg, int E) {
  int e = blockIdx.x * blockDim.x + threadIdx.x;
  if (e < E) atomicAdd(&deg[row[e]], 1);
}

__global__ void scan1(const int* __restrict__ deg, int* __restrict__ rp, int* __restrict__ bsum,
                      int N) {
  __shared__ int sd[256];
  int t = threadIdx.x;
  int i = blockIdx.x * 256 + t;
  int v = (i < N) ? deg[i] : 0;
  sd[t] = v;
  __syncthreads();
  for (int off = 1; off < 256; off <<= 1) {
    int x = (t >= off) ? sd[t - off] : 0;
    __syncthreads();
    sd[t] += x;
    __syncthreads();
  }
  if (i < N) rp[i] = sd[t] - v;
  if (t == 255) bsum[blockIdx.x] = sd[255];
}

__global__ void scan2(int* __restrict__ bsum, int nb) {
  __shared__ int sd[256];
  int t = threadIdx.x;
  int v = (t < nb) ? bsum[t] : 0;
  sd[t] = v;
  __syncthreads();
  for (int off = 1; off < 256; off <<= 1) {
    int x = (t >= off) ? sd[t - off] : 0;
    __syncthreads();
    sd[t] += x;
    __syncthreads();
  }
  if (t < nb) bsum[t] = sd[t] - v;
}

__global__ void scan3(int* __restrict__ rp, const int* __restrict__ bsum, int N, int E) {
  int i = blockIdx.x * 256 + threadIdx.x;
  if (i < N) rp[i] += bsum[blockIdx.x];
  if (i == 0) rp[N] = E;
}

__global__ void scatter_edges(const int* __restrict__ row, const int* __restrict__ col,
                              const int* __restrict__ rp, int* __restrict__ cur,
                              int* __restrict__ scol, int* __restrict__ srow, int E) {
  int e = blockIdx.x * blockDim.x + threadIdx.x;
  if (e >= E) return;
  int r = row[e];
  int p = atomicAdd(&cur[r], 1);
  int idx = rp[r] + p;
  scol[idx] = col[e];
  srow[idx] = r;
}

// ---------------- output-head edge weights (parallel) ----------------
__global__ void edge_wo(const int* __restrict__ srow, const int* __restrict__ scol,
                        const float* __restrict__ s1o, const float* __restrict__ s2o,
                        float* __restrict__ wo, int E) {
  int e = blockIdx.x * blockDim.x + threadIdx.x;
  if (e >= E) return;
  float lg = s1o[srow[e]] + s2o[scol[e]];
  float lr = lg > 0.f ? lg : 0.2f * lg;
  wo[e] = expf(-lr);
}

// ---------------- GAT layer-1 aggregation (fused edge weights): one wave/node ----------------
__global__ __launch_bounds__(64) void agg_att(const ushort* __restrict__ Hb,
                                              const float* __restrict__ s1,
                                              const float* __restrict__ s2,
                                              const int* __restrict__ rp,
                                              const int* __restrict__ scol,
                                              ushort* __restrict__ h1b, int N) {
  int n = blockIdx.x;
  int t = threadIdx.x;          // features t*4..t*4+3 ; head = t>>3
  int head = t >> 3;
  float s1n = s1[n * 8 + head];
  float acc[4] = {0.f, 0.f, 0.f, 0.f};
  float rs = 0.f;
  int beg = rp[n], end = rp[n + 1];
  for (int i = beg; i < end; ++i) {
    int c = scol[i];
    float lg = s1n + s2[c * 8 + head];
    float lr = lg > 0.f ? lg : 0.2f * lg;
    float wv = expf(-lr);
    rs += wv;
    const u16x4 hv = *reinterpret_cast<const u16x4*>(Hb + (size_t)c * 256 + t * 4);
#pragma unroll
    for (int j = 0; j < 4; ++j) acc[j] = fmaf(wv, bf2f(hv[j]), acc[j]);
  }
  float inv = 1.f / (rs + 1e-16f);
  u16x4 ov;
#pragma unroll
  for (int j = 0; j < 4; ++j) {
    float v = acc[j] * inv;
    v = v > 0.f ? v : expm1f(v);
    ov[j] = f2bf(v);
  }
  *reinterpret_cast<u16x4*>(h1b + (size_t)n * 256 + t * 4) = ov;
}

// ---------------- GraphConv aggregation: one wave/node ----------------
__global__ __launch_bounds__(64) void agg_gc(const ushort* __restrict__ Sb,
                                             const int* __restrict__ rp,
                                             const int* __restrict__ scol,
                                             const float* __restrict__ b_gc,
                                             ushort* __restrict__ h2b, int N) {
  int n = blockIdx.x;
  int t = threadIdx.x;
  float acc[4] = {0.f, 0.f, 0.f, 0.f};
  int beg = rp[n], end = rp[n + 1];
  for (int i = beg; i < end; ++i) {
    int c = scol[i];
    const u16x4 sv = *reinterpret_cast<const u16x4*>(Sb + (size_t)c * 256 + t * 4);
#pragma unroll
    for (int j = 0; j < 4; ++j) acc[j] += bf2f(sv[j]);
  }
  const float4 bv = *reinterpret_cast<const float4*>(b_gc + t * 4);
  float o[4] = {acc[0] + bv.x, acc[1] + bv.y, acc[2] + bv.z, acc[3] + bv.w};
  u16x4 ov;
#pragma unroll
  for (int j = 0; j < 4; ++j) ov[j] = f2bf(o[j]);
  *reinterpret_cast<u16x4*>(h2b + (size_t)n * 256 + t * 4) = ov;
}

// ---------------- output head aggregation (precomputed wo, bf16 Ho) + elu + log_softmax ----------------
__global__ __launch_bounds__(64) void agg_out_lsm(const ushort* __restrict__ Hob,
                                                  const float* __restrict__ wo,
                                                  const int* __restrict__ rp,
                                                  const int* __restrict__ scol,
                                                  float* __restrict__ out0, int N) {
  int n = blockIdx.x;
  int t = threadIdx.x;
  float acc = 0.f, rs = 0.f;
  int beg = rp[n], end = rp[n + 1];
  for (int i = beg; i < end; ++i) {
    int c = scol[i];
    float wv = wo[i];
    rs += wv;
    if (t < 40) acc = fmaf(wv, bf2f(Hob[(size_t)c * 40 + t]), acc);
  }
  float hp = acc / (rs + 1e-16f);
  float xo = (t < 40) ? (hp > 0.f ? hp : expm1f(hp)) : -3.0e38f;
  float mx = xo;
#pragma unroll
  for (int m = 1; m < 64; m <<= 1) mx = fmaxf(mx, __shfl_xor(mx, m));
  float ex = (t < 40) ? expf(xo - mx) : 0.f;
  float sum = ex;
#pragma unroll
  for (int m = 1; m < 64; m <<= 1) sum += __shfl_xor(sum, m);
  if (t < 40) out0[(size_t)n * 40 + t] = xo - mx - logf(sum);
}

// ---------------- launch ----------------
extern "C" void kernel_launch(void* const* d_in, const int* in_sizes, int n_in,
                              void* d_out, int out_size, void* d_ws, size_t ws_size,
                              hipStream_t stream) {
  const float* x      = (const float*)d_in[0];
  const int*   ei     = (const int*)d_in[1];
  const float* W_att  = (const float*)d_in[2];
  const float* a1     = (const float*)d_in[3];
  const float* a2     = (const float*)d_in[4];
  const float* W_out  = (const float*)d_in[5];
  const float* a1_out = (const float*)d_in[6];
  const float* a2_out = (const float*)d_in[7];
  const float* W_gc   = (const float*)d_in[8];
  const float* b_gc   = (const float*)d_in[9];
  const float* W_enc  = (const float*)d_in[10];
  const float* b_enc  = (const float*)d_in[11];

  const int N = in_sizes[0] / 256;
  const int E = in_sizes[1] / 2;
  const int* row = ei;
  const int* col = ei + E;

  char* p = (char*)d_ws;
  auto alloc = [&](size_t bytes) -> void* {
    void* r = (void*)p;
    p += (bytes + 255) & ~(size_t)255;
    return r;
  };
  ushort* hbuf = (ushort*)alloc((size_t)N * 256 * 2);  // bf16: H, then support
  ushort* h1b  = (ushort*)alloc((size_t)N * 256 * 2);
  ushort* h2b  = (ushort*)alloc((size_t)N * 256 * 2);
  float* Ho   = (float*)alloc((size_t)N * 40 * 4);
  ushort* Hob = (ushort*)alloc((size_t)N * 40 * 2);
  float* s1   = (float*)alloc((size_t)N * 8 * 4);
  float* s2   = (float*)alloc((size_t)N * 8 * 4);
  float* s1o  = (float*)alloc((size_t)N * 4);
  float* s2o  = (float*)alloc((size_t)N * 4);
  int* deg    = (int*)alloc((size_t)N * 4);
  int* rp     = (int*)alloc((size_t)(N + 1) * 4);
  int* bsum   = (int*)alloc(256 * 4);
  int* scol   = (int*)alloc((size_t)E * 4);
  int* srow   = (int*)alloc((size_t)E * 4);
  float* wo   = (float*)alloc((size_t)E * 4);
  ushort* BpH = (ushort*)alloc((size_t)65536 * 2);
  ushort* BpL = (ushort*)alloc((size_t)65536 * 2);
  ushort* WgH = (ushort*)alloc((size_t)65536 * 2);
  ushort* WgL = (ushort*)alloc((size_t)65536 * 2);
  ushort* WeH = (ushort*)alloc((size_t)32768 * 2);
  ushort* WeL = (ushort*)alloc((size_t)32768 * 2);
  ushort* WoH = (ushort*)alloc((size_t)16384 * 2);
  ushort* WoL = (ushort*)alloc((size_t)16384 * 2);

  float* out0 = (float*)d_out;
  float* outY = out0 + (size_t)N * 40;
  float* outZ = outY + (size_t)N * 128;

  const int nb = (N + 255) / 256;
  const int gblk = (N + 31) / 32;

  // weight packing
  pack_watt_frag<<<dim3(256), dim3(256), 0, stream>>>(W_att, BpH, BpL);
  pack_b<256, 256><<<dim3(256), dim3(256), 0, stream>>>(W_gc, WgH, WgL);
  pack_b<128, 128><<<dim3(128), dim3(256), 0, stream>>>(W_enc, WeH, WeL);
  pack_b<40, 64><<<dim3(64), dim3(256), 0, stream>>>(W_out, WoH, WoL);

  // CSR build (counting sort by row)
  hipMemsetAsync(deg, 0, (size_t)N * 4, stream);
  hist_deg<<<dim3((E + 255) / 256), dim3(256), 0, stream>>>(row, deg, E);
  scan1<<<dim3(nb), dim3(256), 0, stream>>>(deg, rp, bsum, N);
  scan2<<<dim3(1), dim3(256), 0, stream>>>(bsum, nb);
  scan3<<<dim3(nb), dim3(256), 0, stream>>>(rp, bsum, N, E);
  hipMemsetAsync(deg, 0, (size_t)N * 4, stream);  // reuse as cursor
  scatter_edges<<<dim3((E + 255) / 256), dim3(256), 0, stream>>>(row, col, rp, deg, scol, srow, E);

  // layer 1: H = x @ W_att(all heads), bf16 out
  gemm_mfma<256, 256, 2, false, false><<<dim3(gblk), dim3(512), 0, stream>>>(
      x, nullptr, BpH, BpL, nullptr, nullptr, hbuf, N);
  calc_s12<<<dim3((N * 8 + 255) / 256), dim3(256), 0, stream>>>(hbuf, a1, a2, s1, s2, N);
  agg_att<<<dim3(N), dim3(64), 0, stream>>>(hbuf, s1, s2, rp, scol, h1b, N);

  // GraphConv: support bf16 (overwrites hbuf)
  gemm_mfma<256, 256, 2, false, true><<<dim3(gblk), dim3(512), 0, stream>>>(
      nullptr, h1b, WgH, WgL, nullptr, nullptr, hbuf, N);
  agg_gc<<<dim3(N), dim3(64), 0, stream>>>(hbuf, rp, scol, b_gc, h2b, N);

  // output head: Ho f32 (for s12o) + bf16 copy (for gather)
  gemm_mfma<64, 40, 1, false, true><<<dim3(gblk), dim3(512), 0, stream>>>(
      nullptr, h2b, WoH, WoL, nullptr, Ho, Hob, N);
  calc_s12_out<<<dim3((N + 255) / 256), dim3(256), 0, stream>>>(Ho, a1_out, a2_out, s1o, s2o, N);
  edge_wo<<<dim3((E + 255) / 256), dim3(256), 0, stream>>>(srow, scol, s1o, s2o, wo, E);
  agg_out_lsm<<<dim3(N), dim3(64), 0, stream>>>(Hob, wo, rp, scol, out0, N);

  // y, z
  gemm_mfma<128, 128, 0, true, true><<<dim3(gblk), dim3(512), 0, stream>>>(
      nullptr, h1b, WeH, WeL, b_enc, outY, nullptr, N);
  gemm_mfma<128, 128, 0, true, true><<<dim3(gblk), dim3(512), 0, stream>>>(
      nullptr, h2b, WeH, WeL, b_enc, outZ, nullptr, N);
}